// Round 10
// baseline (1305.151 us; speedup 1.0000x reference)
//
#include <hip/hip_runtime.h>
#include <hip/hip_bf16.h>
#include <math.h>

#define NTOK   196
#define BATCH  64
#define TOKENS (BATCH*NTOK)   // 12544
#define DIMD   1024
#define PD     768
#define HEADS  8
#define HD     128
#define DEPTH  6
#define LN_EPS 1e-5f
#define APAD_R 256            // padded A rows per batch (for 128-tiles)
#define APAD_C 224            // padded K dim for A@G (7*32)

typedef __hip_bfloat16 bf16;
typedef __attribute__((ext_vector_type(8))) short bf16x8;
typedef __attribute__((ext_vector_type(4))) float f32x4;

typedef const __attribute__((address_space(1))) void* gptr_t;
typedef __attribute__((address_space(3))) void* lptr_t;

__device__ __forceinline__ void gl_lds16(const bf16* g, bf16* l) {
  __builtin_amdgcn_global_load_lds((gptr_t)(const void*)g, (lptr_t)(void*)l, 16, 0, 0);
}
__device__ __forceinline__ unsigned short bfbits(float f) {
  bf16 h = __float2bfloat16(f);
  return *(unsigned short*)&h;
}

// XCD-aware bijective swizzle (requires nwg % 8 == 0, true for all call sites):
// physical block f runs work item (f%8)*(nwg/8) + f/8, so each XCD gets a
// CONTIGUOUS range of work ids -> operand-panel-sharing blocks co-locate on one L2.
__device__ __forceinline__ void xcd_swizzle(int& bx, int& by, int& bz) {
  const int gx = gridDim.x, gy = gridDim.y;
  const int nwg = gx*gy*gridDim.z;
  const int flat = blockIdx.x + gx*(blockIdx.y + gy*blockIdx.z);
  const int swz = (flat & 7)*(nwg >> 3) + (flat >> 3);
  bx = swz % gx;
  const int rest = swz / gx;
  by = rest % gy;
  bz = rest / gy;
}

// ================= generic MFMA GEMM: C[m][n] = sum_k A[m][k] * Bt[n][k] =================
// 128x128 tile, BK=64 (two [128][32] chunks per barrier pair). Single LDS buffer (32 KB),
// drain per iteration (r0/r1/r7/r9 showed sync policy and iteration count are both
// don't-cares: staging path is the limiter at ~10 B/cyc/CU). K-accumulation order
// identical to BK=32 -> bit-identical output. mode 0: Cf = acc*alpha (+bias)(+bf16 res);
// mode 1: Cb = bf16(acc)
__global__ __launch_bounds__(256) void gemm_mfma(
    const bf16* __restrict__ A, int lda, long aStride,
    const bf16* __restrict__ Bt, int ldb, long bStride,
    int K, int mode,
    float* __restrict__ Cf, bf16* __restrict__ Cb, int ldc, long cStride,
    const float* __restrict__ bias, const bf16* __restrict__ resb, long resStride,
    float alpha, int Mb, int Nb) {
  __shared__ __align__(16) bf16 As[2*128*32];   // 16 KB
  __shared__ __align__(16) bf16 Bs[2*128*32];   // 16 KB
  const int CH = 128*32;
  int bx, by, bz;
  xcd_swizzle(bx, by, bz);
  const int z = bz;
  A  += (long)z*aStride;
  Bt += (long)z*bStride;
  const int m0 = by*128, n0 = bx*128;
  const int tid = threadIdx.x, lane = tid & 63, wv = tid >> 6;
  const int lrow = lane >> 2, lchunk = lane & 3;
  const bf16* ga = A + (long)(m0 + wv*32 + lrow)*lda + lchunk*8;
  const bf16* gb = Bt + (long)(n0 + wv*32 + lrow)*ldb + lchunk*8;
  bf16* lA = As + (wv*32)*32;
  bf16* lB = Bs + (wv*32)*32;
  const int mBase = (wv & 1)*64, nBase = (wv >> 1)*64;
  const int fr = lane & 15, fq = lane >> 4;

  f32x4 acc[4][4];
  #pragma unroll
  for (int i = 0; i < 4; i++)
    #pragma unroll
    for (int j = 0; j < 4; j++) acc[i][j] = (f32x4){0.f,0.f,0.f,0.f};

  const int nk = K >> 6;   // BK=64; all call sites have K % 64 == 0
  for (int t = 0; t < nk; ++t) {
    const int k0 = t << 6;
    #pragma unroll
    for (int c = 0; c < 2; c++) {
      gl_lds16(ga + k0 + c*32,          lA + c*CH);
      gl_lds16(ga + k0 + c*32 + 16*lda, lA + c*CH + 16*32);
      gl_lds16(gb + k0 + c*32,          lB + c*CH);
      gl_lds16(gb + k0 + c*32 + 16*ldb, lB + c*CH + 16*32);
    }
    asm volatile("s_waitcnt vmcnt(0)" ::: "memory");
    __syncthreads();
    #pragma unroll
    for (int c = 0; c < 2; c++) {
      const bf16* Ab = As + c*CH;
      const bf16* Bb = Bs + c*CH;
      bf16x8 af[4], bfr[4];
      #pragma unroll
      for (int mi = 0; mi < 4; mi++)
        af[mi] = *(const bf16x8*)(Ab + (mBase + mi*16 + fr)*32 + fq*8);
      #pragma unroll
      for (int ni = 0; ni < 4; ni++)
        bfr[ni] = *(const bf16x8*)(Bb + (nBase + ni*16 + fr)*32 + fq*8);
      #pragma unroll
      for (int mi = 0; mi < 4; mi++)
        #pragma unroll
        for (int ni = 0; ni < 4; ni++)
          acc[mi][ni] = __builtin_amdgcn_mfma_f32_16x16x32_bf16(af[mi], bfr[ni], acc[mi][ni], 0, 0, 0);
    }
    __syncthreads();
  }

  #pragma unroll
  for (int mi = 0; mi < 4; mi++)
    #pragma unroll
    for (int ni = 0; ni < 4; ni++)
      #pragma unroll
      for (int r = 0; r < 4; r++) {
        int gm = m0 + mBase + mi*16 + fq*4 + r;
        int gn = n0 + nBase + ni*16 + fr;
        if (gm >= Mb || gn >= Nb) continue;
        float v = acc[mi][ni][r] * alpha;
        if (mode == 0) {
          if (bias) v += bias[gn];
          if (resb) v += __bfloat162float(resb[(long)z*resStride + (long)gm*ldc + gn]);
          Cf[(long)z*cStride + (long)gm*ldc + gn] = v;
        } else {
          Cb[(long)z*cStride + (long)gm*ldc + gn] = __float2bfloat16(v);
        }
      }
}

// ================= AV GEMM: x[z] = Apad[z] @ Gt[z]^T + xnb[z], full-K staging =================
// 128x128 tile, K=224 staged entirely in LDS (112 KB total; 160 KB available -- the
// round-4/5 container failures were proven infra-flake by r8/r9 identical-source
// retry). ONE vmcnt(0)+barrier per block instead of a K-loop; 112 MFMAs barrier-free.
// Staging volume HALVES vs the 64^2 variant (1024 x 112 KB = 114 MB vs 229 MB).
// Chunk order = K order -> accumulation identical -> bit-identical output.
__global__ __launch_bounds__(256) void gemm_av(
    const bf16* __restrict__ Apad, const bf16* __restrict__ Gt,
    const bf16* __restrict__ resb, float* __restrict__ Cf) {
  __shared__ __align__(16) bf16 As[7*128*32];   // 56 KB
  __shared__ __align__(16) bf16 Bs[7*128*32];   // 56 KB
  const int CH = 128*32;
  int bx, by, bz;
  xcd_swizzle(bx, by, bz);
  const int z = bz, m0 = by*128, n0 = bx*128;
  const int tid = threadIdx.x, lane = tid & 63, wv = tid >> 6;
  const int lrow = lane >> 2, lchunk = lane & 3;
  const bf16* ga = Apad + ((long)z*APAD_R + m0 + wv*32 + lrow)*APAD_C + lchunk*8;
  const bf16* gb = Gt   + ((long)z*DIMD  + n0 + wv*32 + lrow)*APAD_C + lchunk*8;
  bf16* lA = As + (wv*32)*32;
  bf16* lB = Bs + (wv*32)*32;
  #pragma unroll
  for (int c = 0; c < 7; c++) {
    gl_lds16(ga + c*32,             lA + c*CH);
    gl_lds16(ga + c*32 + 16*APAD_C, lA + c*CH + 16*32);
    gl_lds16(gb + c*32,             lB + c*CH);
    gl_lds16(gb + c*32 + 16*APAD_C, lB + c*CH + 16*32);
  }
  asm volatile("s_waitcnt vmcnt(0)" ::: "memory");
  __syncthreads();

  const int mBase = (wv & 1)*64, nBase = (wv >> 1)*64;
  const int fr = lane & 15, fq = lane >> 4;
  f32x4 acc[4][4];
  #pragma unroll
  for (int i = 0; i < 4; i++)
    #pragma unroll
    for (int j = 0; j < 4; j++) acc[i][j] = (f32x4){0.f,0.f,0.f,0.f};

  #pragma unroll
  for (int c = 0; c < 7; c++) {
    const bf16* Ab = As + c*CH;
    const bf16* Bb = Bs + c*CH;
    bf16x8 af[4], bfr[4];
    #pragma unroll
    for (int mi = 0; mi < 4; mi++)
      af[mi] = *(const bf16x8*)(Ab + (mBase + mi*16 + fr)*32 + fq*8);
    #pragma unroll
    for (int ni = 0; ni < 4; ni++)
      bfr[ni] = *(const bf16x8*)(Bb + (nBase + ni*16 + fr)*32 + fq*8);
    #pragma unroll
    for (int mi = 0; mi < 4; mi++)
      #pragma unroll
      for (int ni = 0; ni < 4; ni++)
        acc[mi][ni] = __builtin_amdgcn_mfma_f32_16x16x32_bf16(af[mi], bfr[ni], acc[mi][ni], 0, 0, 0);
  }

  #pragma unroll
  for (int mi = 0; mi < 4; mi++)
    #pragma unroll
    for (int ni = 0; ni < 4; ni++)
      #pragma unroll
      for (int r = 0; r < 4; r++) {
        int gm = m0 + mBase + mi*16 + fq*4 + r;
        int gn = n0 + nBase + ni*16 + fr;
        if (gm >= NTOK) continue;
        float v = acc[mi][ni][r]
                + __bfloat162float(resb[(long)z*NTOK*DIMD + (long)gm*DIMD + gn]);
        Cf[(long)z*NTOK*DIMD + (long)gm*DIMD + gn] = v;
      }
}

// ====== fused QKT+softmax: per batch z, 64-row tile x full 224-col width ======
// logits = xm[z] @ xnb[z]^T (fp32 acc), row-softmax with max-sub, writes bf16 Apad.
// Depth-3 ring pipeline (1 block/CU -> prefetch is the only latency hiding).
__global__ __launch_bounds__(256) void gemm_qs(
    const bf16* __restrict__ xmp, const bf16* __restrict__ xnbp,
    bf16* __restrict__ Apad, float scale) {
  __shared__ __align__(16) bf16 As[3][64*32];
  __shared__ __align__(16) bf16 Bs[3][224*32];
  const int ABUF = 64*32, BBUF = 224*32;
  int bx, by, bz;
  xcd_swizzle(bx, by, bz);
  const int z = bz;
  const int y0 = by*64;                         // 0,64,128,192
  const bf16* A  = xmp  + (long)z*NTOK*DIMD;
  const bf16* Bt = xnbp + (long)z*NTOK*DIMD;
  const int tid = threadIdx.x, lane = tid & 63, wv = tid >> 6;
  const int lrow = lane >> 2, lchunk = lane & 3;
  const bf16* ga = A + (long)(y0 + wv*16 + lrow)*DIMD + lchunk*8;
  bf16* lA = &As[0][(wv*16)*32];
  const bf16* gb = Bt + (long)(wv*64 + lrow)*DIMD + lchunk*8;
  bf16* lB = &Bs[0][(wv*64)*32];
  const int nIss = (wv < 3) ? 4 : 2;            // per-wave B issues (+1 A issue)
  const int fr = lane & 15, fq = lane >> 4;

  f32x4 acc[14];
  #pragma unroll
  for (int j = 0; j < 14; j++) acc[j] = (f32x4){0.f,0.f,0.f,0.f};

  const int nk = 32;
  // prologue: stage tiles 0 and 1
  #pragma unroll
  for (int p = 0; p < 2; p++) {
    gl_lds16(ga + p*32, lA + p*ABUF);
    for (int i = 0; i < nIss; i++)
      gl_lds16(gb + p*32 + (long)i*16*DIMD, lB + p*BBUF + i*16*32);
  }
  for (int t = 0; t < nk; ++t) {
    const int cur = t % 3;
    if (t + 2 < nk) {
      const int nb = (t + 2) % 3;
      const int k2 = (t + 2) << 5;
      gl_lds16(ga + k2, lA + nb*ABUF);
      for (int i = 0; i < nIss; i++)
        gl_lds16(gb + k2 + (long)i*16*DIMD, lB + nb*BBUF + i*16*32);
    }
    const int ahead = (nk - 1 - t > 2) ? 2 : (nk - 1 - t);
    if (wv < 3) {      // 5 loads/stage
      if (ahead == 2)      asm volatile("s_waitcnt vmcnt(10)" ::: "memory");
      else if (ahead == 1) asm volatile("s_waitcnt vmcnt(5)"  ::: "memory");
      else                 asm volatile("s_waitcnt vmcnt(0)"  ::: "memory");
    } else {           // 3 loads/stage
      if (ahead == 2)      asm volatile("s_waitcnt vmcnt(6)"  ::: "memory");
      else if (ahead == 1) asm volatile("s_waitcnt vmcnt(3)"  ::: "memory");
      else                 asm volatile("s_waitcnt vmcnt(0)"  ::: "memory");
    }
    __builtin_amdgcn_s_barrier();
    const bf16* Ab = &As[cur][0];
    const bf16* Bb = &Bs[cur][0];
    bf16x8 af = *(const bf16x8*)(Ab + (wv*16 + fr)*32 + fq*8);
    #pragma unroll
    for (int j = 0; j < 14; j++) {
      bf16x8 bfr = *(const bf16x8*)(Bb + (j*16 + fr)*32 + fq*8);
      acc[j] = __builtin_amdgcn_mfma_f32_16x16x32_bf16(af, bfr, acc[j], 0, 0, 0);
    }
    asm volatile("s_waitcnt lgkmcnt(0)" ::: "memory");
    __builtin_amdgcn_s_barrier();
  }

  // per-row softmax: row = y0 + wv*16 + fq*4 + r; cols j*16 + fr
  #pragma unroll
  for (int r = 0; r < 4; r++) {
    float mx = -INFINITY;
    #pragma unroll
    for (int j = 0; j < 14; j++) {
      int col = j*16 + fr;
      if (col < NTOK) mx = fmaxf(mx, acc[j][r]);
    }
    #pragma unroll
    for (int off = 1; off < 16; off <<= 1) mx = fmaxf(mx, __shfl_xor(mx, off));
    float e[14];
    float s = 0.f;
    #pragma unroll
    for (int j = 0; j < 14; j++) {
      int col = j*16 + fr;
      e[j] = (col < NTOK) ? __expf((acc[j][r] - mx) * scale) : 0.f;
      s += e[j];
    }
    #pragma unroll
    for (int off = 1; off < 16; off <<= 1) s += __shfl_xor(s, off);
    float inv = 1.f / s;
    int grow = y0 + wv*16 + fq*4 + r;
    bf16* dst = Apad + ((long)z*APAD_R + grow)*APAD_C;
    #pragma unroll
    for (int j = 0; j < 14; j++) {
      int col = j*16 + fr;
      float outv = (grow < NTOK) ? e[j]*inv : 0.f;   // col>=196 -> e=0 -> writes 0
      dst[col] = __float2bfloat16(outv);
    }
  }
}

// ====== V-GEMM direct-Gt: Gt[z][h*128+d][t] = sum_e WVt[d][e]*xnb[z*196+t][h*128+e] ======
// K=128: stage the ENTIRE K up front (4 chunks), one drain, then barrier-free MFMA loop.
__global__ __launch_bounds__(256) void gemm_v(
    const bf16* __restrict__ WVt, const bf16* __restrict__ xnb, bf16* __restrict__ Gt) {
  __shared__ __align__(16) bf16 As[4][128*32];   // 32 KB
  __shared__ __align__(16) bf16 Bs[4][128*32];   // 32 KB
  const int CH = 128*32;
  int bx, by, bz;
  xcd_swizzle(bx, by, bz);
  const int z = bz, h = by, n0 = bx*128;
  const int tid = threadIdx.x, lane = tid & 63, wv = tid >> 6;
  const int lrow = lane >> 2, lchunk = lane & 3;
  const bf16* ga = WVt + (long)(wv*32 + lrow)*HD + lchunk*8;
  const bf16* gb = xnb + (long)(z*NTOK + n0 + wv*32 + lrow)*DIMD + h*HD + lchunk*8;
  bf16* lA = &As[0][(wv*32)*32];
  bf16* lB = &Bs[0][(wv*32)*32];
  const int mBase = (wv & 1)*64, nBase = (wv >> 1)*64;
  const int fr = lane & 15, fq = lane >> 4;

  f32x4 acc[4][4];
  #pragma unroll
  for (int i = 0; i < 4; i++)
    #pragma unroll
    for (int j = 0; j < 4; j++) acc[i][j] = (f32x4){0.f,0.f,0.f,0.f};

  #pragma unroll
  for (int c = 0; c < 4; c++) {
    gl_lds16(ga + c*32,           lA + c*CH);
    gl_lds16(ga + c*32 + 16*HD,   lA + c*CH + 16*32);
    gl_lds16(gb + c*32,           lB + c*CH);
    gl_lds16(gb + c*32 + 16*DIMD, lB + c*CH + 16*32);
  }
  asm volatile("s_waitcnt vmcnt(0)" ::: "memory");
  __syncthreads();

  #pragma unroll
  for (int c = 0; c < 4; c++) {
    const bf16* Ab = &As[c][0];
    const bf16* Bb = &Bs[c][0];
    bf16x8 af[4], bfr[4];
    #pragma unroll
    for (int mi = 0; mi < 4; mi++)
      af[mi] = *(const bf16x8*)(Ab + (mBase + mi*16 + fr)*32 + fq*8);
    #pragma unroll
    for (int ni = 0; ni < 4; ni++)
      bfr[ni] = *(const bf16x8*)(Bb + (nBase + ni*16 + fr)*32 + fq*8);
    #pragma unroll
    for (int mi = 0; mi < 4; mi++)
      #pragma unroll
      for (int ni = 0; ni < 4; ni++)
        acc[mi][ni] = __builtin_amdgcn_mfma_f32_16x16x32_bf16(af[mi], bfr[ni], acc[mi][ni], 0, 0, 0);
  }

  #pragma unroll
  for (int mi = 0; mi < 4; mi++)
    #pragma unroll
    for (int ni = 0; ni < 4; ni++)
      #pragma unroll
      for (int r = 0; r < 4; r++) {
        int gm = mBase + mi*16 + fq*4 + r;          // output dim within head (0..127)
        int gn = n0 + nBase + ni*16 + fr;           // token
        if (gn < NTOK)
          Gt[((long)z*DIMD + h*HD + gm)*APAD_C + gn] = __float2bfloat16(acc[mi][ni][r]);
        else if (gn < APAD_C)
          Gt[((long)z*DIMD + h*HD + gm)*APAD_C + gn] = __float2bfloat16(0.f);
      }
}

// ================= classifier split-K (K=128: full up-front staging) =================
__global__ __launch_bounds__(256) void gemm_cls(
    const bf16* __restrict__ A, const bf16* __restrict__ Bt,
    float* __restrict__ Cp) {
  __shared__ __align__(16) bf16 As[4][64*32];    // 16 KB
  __shared__ __align__(16) bf16 Bs[4][128*32];   // 32 KB
  const int ACH = 64*32, BCH = 128*32;
  const int n0 = blockIdx.x*128, kz = blockIdx.y;
  const int tid = threadIdx.x, lane = tid & 63, wv = tid >> 6;
  const bf16* ga = A + (tid>>2)*DIMD + kz*128 + (tid&3)*8;
  const bf16* gb = Bt + (long)(n0 + wv*32 + (lane>>2))*DIMD + kz*128 + (lane&3)*8;
  bf16* lA = &As[0][wv*512];
  bf16* lB = &Bs[0][(wv*32)*32];
  const int fr = lane & 15, fq = lane >> 4;
  f32x4 acc[4][2];
  #pragma unroll
  for (int i = 0; i < 4; i++)
    #pragma unroll
    for (int j = 0; j < 2; j++) acc[i][j] = (f32x4){0.f,0.f,0.f,0.f};
  #pragma unroll
  for (int it = 0; it < 4; it++) {
    gl_lds16(ga + it*32, lA + it*ACH);
    gl_lds16(gb + it*32,            lB + it*BCH);
    gl_lds16(gb + it*32 + 16*DIMD,  lB + it*BCH + 16*32);
  }
  asm volatile("s_waitcnt vmcnt(0)" ::: "memory");
  __syncthreads();
  #pragma unroll
  for (int it = 0; it < 4; it++) {
    const bf16* Ab = &As[it][0];
    const bf16* Bb = &Bs[it][0];
    bf16x8 af[4], bfr[2];
    #pragma unroll
    for (int mi = 0; mi < 4; mi++)
      af[mi] = *(const bf16x8*)(Ab + (mi*16 + fr)*32 + fq*8);
    #pragma unroll
    for (int ni = 0; ni < 2; ni++)
      bfr[ni] = *(const bf16x8*)(Bb + (wv*32 + ni*16 + fr)*32 + fq*8);
    #pragma unroll
    for (int mi = 0; mi < 4; mi++)
      #pragma unroll
      for (int ni = 0; ni < 2; ni++)
        acc[mi][ni] = __builtin_amdgcn_mfma_f32_16x16x32_bf16(af[mi], bfr[ni], acc[mi][ni], 0, 0, 0);
  }
  #pragma unroll
  for (int mi = 0; mi < 4; mi++)
    #pragma unroll
    for (int ni = 0; ni < 2; ni++)
      #pragma unroll
      for (int r = 0; r < 4; r++) {
        int gm = mi*16 + fq*4 + r;
        int gn = n0 + wv*32 + ni*16 + fr;
        Cp[((long)kz*64 + gm)*DIMD + gn] = acc[mi][ni][r];
      }
}

__global__ __launch_bounds__(256) void cls_reduce(
    const float* __restrict__ Cp, const float* __restrict__ bias,
    float* __restrict__ out) {
  int i = blockIdx.x*256 + threadIdx.x;
  int m = i / 1000, n = i - m*1000;
  float s = bias[n];
  #pragma unroll
  for (int kz = 0; kz < 8; kz++) s += Cp[((long)kz*64 + m)*DIMD + n];
  out[i] = s;
}

// ================= patchify + LN1 (dim 768) -> bf16 =================
__global__ __launch_bounds__(256) void patchify_ln(
    const float* __restrict__ img, const float* __restrict__ g,
    const float* __restrict__ b, bf16* __restrict__ out) {
  int t = blockIdx.x;
  int bi = t / NTOK, n = t % NTOK;
  int ph = n / 14, pw = n % 14;
  __shared__ float vals[PD];
  __shared__ float part[8];
  int tid = threadIdx.x;
  int lane = tid & 63, wv = tid >> 6;
  for (int j = tid; j < PD; j += 256) {
    int p1 = j / 48, rem = j % 48, p2 = rem / 3, c = rem % 3;
    vals[j] = img[(((long)bi*3 + c)*224 + (ph*16 + p1))*224 + (pw*16 + p2)];
  }
  __syncthreads();
  float s = 0.f;
  for (int j = tid; j < PD; j += 256) s += vals[j];
  #pragma unroll
  for (int off = 1; off < 64; off <<= 1) s += __shfl_xor(s, off);
  if (lane == 0) part[wv] = s;
  __syncthreads();
  float mean = (part[0]+part[1]+part[2]+part[3]) / (float)PD;
  float s2 = 0.f;
  for (int j = tid; j < PD; j += 256) { float d = vals[j]-mean; s2 += d*d; }
  #pragma unroll
  for (int off = 1; off < 64; off <<= 1) s2 += __shfl_xor(s2, off);
  if (lane == 0) part[4+wv] = s2;
  __syncthreads();
  float rstd = rsqrtf((part[4]+part[5]+part[6]+part[7])/(float)PD + LN_EPS);
  for (int j = tid; j < PD; j += 256)
    out[(long)t*PD + j] = __float2bfloat16((vals[j]-mean)*rstd*g[j] + b[j]);
}

// ================= LayerNorm rows (dim=1024): optional fp32 out, optional bf16 out =================
__global__ __launch_bounds__(256) void ln_rows2(
    const float* __restrict__ in, const float* __restrict__ g,
    const float* __restrict__ b, const float* __restrict__ pos,
    float* __restrict__ outf, ushort4* __restrict__ outb) {
  long t = blockIdx.x;
  int tid = threadIdx.x;
  int lane = tid & 63, wv = tid >> 6;
  float4 v = ((const float4*)(in + t*DIMD))[tid];
  float s  = v.x+v.y+v.z+v.w;
  float s2 = v.x*v.x+v.y*v.y+v.z*v.z+v.w*v.w;
  #pragma unroll
  for (int off = 1; off < 64; off <<= 1) {
    s  += __shfl_xor(s, off);
    s2 += __shfl_xor(s2, off);
  }
  __shared__ float ps[4], pq[4];
  if (lane == 0) { ps[wv] = s; pq[wv] = s2; }
  __syncthreads();
  s  = ps[0]+ps[1]+ps[2]+ps[3];
  s2 = pq[0]+pq[1]+pq[2]+pq[3];
  float mean = s*(1.f/1024.f);
  float var  = s2*(1.f/1024.f) - mean*mean;
  float rstd = rsqrtf(var + LN_EPS);
  float4 gg = ((const float4*)g)[tid];
  float4 bb = ((const float4*)b)[tid];
  float4 o;
  o.x = (v.x-mean)*rstd*gg.x + bb.x;
  o.y = (v.y-mean)*rstd*gg.y + bb.y;
  o.z = (v.z-mean)*rstd*gg.z + bb.z;
  o.w = (v.w-mean)*rstd*gg.w + bb.w;
  if (pos) {
    float4 pp = ((const float4*)(pos + (long)(t % NTOK)*DIMD))[tid];
    o.x += pp.x; o.y += pp.y; o.z += pp.z; o.w += pp.w;
  }
  if (outf) ((float4*)(outf + t*DIMD))[tid] = o;
  if (outb) {
    ushort4 u;
    u.x = bfbits(o.x); u.y = bfbits(o.y); u.z = bfbits(o.z); u.w = bfbits(o.w);
    outb[t*256 + tid] = u;
  }
}

// ================= cast + transpose weights: fp32 [R][C] -> bf16 [C][R] =================
__global__ void castT(const float* __restrict__ src, bf16* __restrict__ dst, int R, int C) {
  __shared__ float t[32][33];
  int rb = blockIdx.y*32, cb = blockIdx.x*32;
  int tx = threadIdx.x, ty = threadIdx.y;  // (32,8)
  for (int i = ty; i < 32; i += 8)
    if (rb+i < R && cb+tx < C) t[i][tx] = src[(long)(rb+i)*C + cb+tx];
  __syncthreads();
  for (int i = ty; i < 32; i += 8)
    if (cb+i < C && rb+tx < R) dst[(long)(cb+i)*R + rb+tx] = __float2bfloat16(t[tx][i]);
}

// ================= natural cast fp32 -> bf16 (elementwise, float4) =================
__global__ __launch_bounds__(256) void castN(
    const float* __restrict__ src, ushort4* __restrict__ dst) {
  int i = blockIdx.x*256 + threadIdx.x;
  float4 v = ((const float4*)src)[i];
  ushort4 u;
  u.x = bfbits(v.x); u.y = bfbits(v.y); u.z = bfbits(v.z); u.w = bfbits(v.w);
  dst[i] = u;
}

// ================= mean over tokens -> bf16 =================
__global__ __launch_bounds__(256) void mean_tokens(
    const float* __restrict__ x, bf16* __restrict__ outb) {
  int b = blockIdx.x;
  int d = blockIdx.y*256 + threadIdx.x;
  const float* p = x + (long)b*NTOK*DIMD + d;
  float s = 0.f;
  #pragma unroll 4
  for (int n = 0; n < NTOK; n++) s += p[(long)n*DIMD];
  outb[(long)b*DIMD + d] = __float2bfloat16(s * (1.f/196.f));
}

extern "C" void kernel_launch(void* const* d_in, const int* in_sizes, int n_in,
                              void* d_out, int out_size, void* d_ws, size_t ws_size,
                              hipStream_t stream) {
  (void)in_sizes; (void)n_in; (void)out_size; (void)ws_size;
  const float* image = (const float*)d_in[0];
  const float* ln1_g = (const float*)d_in[1];
  const float* ln1_b = (const float*)d_in[2];
  const float* W_emb = (const float*)d_in[3];
  const float* b_emb = (const float*)d_in[4];
  const float* ln2_g = (const float*)d_in[5];
  const float* ln2_b = (const float*)d_in[6];
  const float* pos   = (const float*)d_in[7];
  const float* norm_g= (const float*)d_in[8];
  const float* norm_b= (const float*)d_in[9];
  const float* WV    = (const float*)d_in[10];
  const float* WK    = (const float*)d_in[11];
  const float* WQ    = (const float*)d_in[12];
  const float* lastW = (const float*)d_in[13];
  const float* lastb = (const float*)d_in[14];
  float* out = (float*)d_out;

  char* W = (char*)d_ws;
  float* x     = (float*)(W);                      // 51,380,224
  bf16*  xnb   = (bf16*) (W + 51380224);           // 25,690,112
  bf16*  xm    = (bf16*) (W + 77070336);           // 25.7MB in 51.6MB slab (alias Xp; overread zone)
  bf16*  Xp    = xm;
  // slabB: embed-phase xn (fp32 51.4 MB) OR layer-phase Gt+Apad
  float* xn    = (float*)(W + 128712704);
  bf16*  Gt    = (bf16*) (W + 128712704);          // 29,360,128
  bf16*  Apad  = (bf16*) (W + 167907328);          //  7,340,032
  bf16*  WembT = (bf16*) (W + 180092928);          //  1,572,864
  bf16*  WQb   = (bf16*) (W + 181665792);          //  2,097,152 (natural layout)
  bf16*  WKb   = (bf16*) (W + 183762944);          //  2,097,152 (natural layout)
  bf16*  WVt   = (bf16*) (W + 185860096);          //     32,768
  bf16*  lastWT= (bf16*) (W + 185892864);          //  2,097,152
  bf16*  meanxb= (bf16*) (W + 187990016);          //    131,072
  float* clsPart=(float*)(W + 188121088);          //  2,097,152
  bf16*  Mt    = (bf16*) (W + 190218240);          //  2,097,152 (M^T = WK @ WQ^T)

  dim3 blk(256);
  const float scale = 0.08838834764831845f;  // 128^-0.5
  const long ZR = 0;

  // weight casts
  castT<<<dim3(32, 24), dim3(32, 8), 0, stream>>>(W_emb, WembT, PD, DIMD);
  castN<<<1024, blk, 0, stream>>>(WQ, (ushort4*)WQb);
  castN<<<1024, blk, 0, stream>>>(WK, (ushort4*)WKb);
  castT<<<dim3(4, 4),  dim3(32, 8), 0, stream>>>(WV, WVt, HD, HD);
  castT<<<dim3(32, 32), dim3(32, 8), 0, stream>>>(lastW, lastWT, DIMD, 1000);
  // Mt[j][i] = sum_k WK[j][k]*WQ[i][k]  (= (WQ @ WK^T)^T)
  gemm_mfma<<<dim3(8, 8, 1), blk, 0, stream>>>(
      WKb, DIMD, ZR, WQb, DIMD, ZR, DIMD, 1,
      nullptr, Mt, DIMD, ZR, nullptr, nullptr, ZR, 1.f, DIMD, DIMD);

  // patch embed
  patchify_ln<<<TOKENS, blk, 0, stream>>>(image, ln1_g, ln1_b, Xp);
  gemm_mfma<<<dim3(8, 98, 1), blk, 0, stream>>>(
      Xp, PD, ZR, WembT, PD, ZR, PD, 0,
      xn, nullptr, DIMD, ZR, b_emb, nullptr, ZR, 1.f, TOKENS, DIMD);
  ln_rows2<<<TOKENS, blk, 0, stream>>>(xn, ln2_g, ln2_b, pos, x, nullptr);

  for (int l = 0; l < DEPTH; l++) {
    // xnb = bf16(LN(x))
    ln_rows2<<<TOKENS, blk, 0, stream>>>(x, norm_g, norm_b, nullptr, nullptr, (ushort4*)xnb);
    // xm = xnb @ M
    gemm_mfma<<<dim3(8, 98, 1), blk, 0, stream>>>(
        xnb, DIMD, ZR, Mt, DIMD, ZR, DIMD, 1,
        nullptr, xm, DIMD, ZR, nullptr, nullptr, ZR, 1.f, TOKENS, DIMD);
    // Apad = softmax(xm @ xnb^T * scale), fused, pads zeroed
    gemm_qs<<<dim3(1, 4, BATCH), blk, 0, stream>>>(xm, xnb, Apad, scale);
    // Gt[b][dim][tok] = WV^T @ xn^T  (direct transposed layout, pad cols zeroed)
    gemm_v<<<dim3(2, HEADS, BATCH), blk, 0, stream>>>(WVt, xnb, Gt);
    // x = Apad @ G + xnb (bf16 residual), full-K staged, 128x128 tiles
    gemm_av<<<dim3(8, 2, BATCH), blk, 0, stream>>>(Apad, Gt, xnb, x);
  }

  // classifier
  mean_tokens<<<dim3(BATCH, 4), blk, 0, stream>>>(x, meanxb);
  gemm_cls<<<dim3(8, 8), blk, 0, stream>>>(meanxb, lastWT, clsPart);
  cls_reduce<<<250, blk, 0, stream>>>(clsPart, lastb, out);
}

// Round 11
// 1116.529 us; speedup vs baseline: 1.1689x; 1.1689x over previous
//
#include <hip/hip_runtime.h>
#include <hip/hip_bf16.h>
#include <math.h>

#define NTOK   196
#define BATCH  64
#define TOKENS (BATCH*NTOK)   // 12544
#define DIMD   1024
#define PD     768
#define HEADS  8
#define HD     128
#define DEPTH  6
#define LN_EPS 1e-5f
#define APAD_R 256            // padded A rows per batch (for 128-tiles)
#define APAD_C 224            // padded K dim for A@G (7*32)

typedef __hip_bfloat16 bf16;
typedef __attribute__((ext_vector_type(8))) short bf16x8;
typedef __attribute__((ext_vector_type(4))) float f32x4;

typedef const __attribute__((address_space(1))) void* gptr_t;
typedef __attribute__((address_space(3))) void* lptr_t;

__device__ __forceinline__ void gl_lds16(const bf16* g, bf16* l) {
  __builtin_amdgcn_global_load_lds((gptr_t)(const void*)g, (lptr_t)(void*)l, 16, 0, 0);
}
__device__ __forceinline__ unsigned short bfbits(float f) {
  bf16 h = __float2bfloat16(f);
  return *(unsigned short*)&h;
}

// XCD-aware bijective swizzle (requires nwg % 8 == 0, true for all call sites):
// physical block f runs work item (f%8)*(nwg/8) + f/8, so each XCD gets a
// CONTIGUOUS range of work ids -> operand-panel-sharing blocks co-locate on one L2.
__device__ __forceinline__ void xcd_swizzle(int& bx, int& by, int& bz) {
  const int gx = gridDim.x, gy = gridDim.y;
  const int nwg = gx*gy*gridDim.z;
  const int flat = blockIdx.x + gx*(blockIdx.y + gy*blockIdx.z);
  const int swz = (flat & 7)*(nwg >> 3) + (flat >> 3);
  bx = swz % gx;
  const int rest = swz / gx;
  by = rest % gy;
  bz = rest / gy;
}

// ================= generic MFMA GEMM: C[m][n] = sum_k A[m][k] * Bt[n][k] =================
// 256x128 tile, 512 threads (8 waves, each a 64x64 quadrant: 4 rows x 2 cols of waves),
// BK=64 (two [.][32] chunks per barrier pair). Staging volume per output element is
// 0.75x the 128x128 tile (the measured limiter is the ~10 B/cyc/CU staging service,
// r0-r9: sync policy / depth / BK all null). Single LDS buffer 48 KB -> 2-3 blocks/CU.
// K-accumulation order per fragment unchanged -> bit-identical output.
// mode 0: Cf = acc*alpha (+bias)(+bf16 res); mode 1: Cb = bf16(acc)
__global__ __launch_bounds__(512) void gemm_mfma(
    const bf16* __restrict__ A, int lda, long aStride,
    const bf16* __restrict__ Bt, int ldb, long bStride,
    int K, int mode,
    float* __restrict__ Cf, bf16* __restrict__ Cb, int ldc, long cStride,
    const float* __restrict__ bias, const bf16* __restrict__ resb, long resStride,
    float alpha, int Mb, int Nb) {
  __shared__ __align__(16) bf16 As[2*256*32];   // 32 KB (2 chunks x 256 rows x 32 cols)
  __shared__ __align__(16) bf16 Bs[2*128*32];   // 16 KB
  const int CHA = 256*32, CHB = 128*32;
  int bx, by, bz;
  xcd_swizzle(bx, by, bz);
  const int z = bz;
  A  += (long)z*aStride;
  Bt += (long)z*bStride;
  const int m0 = by*256, n0 = bx*128;
  const int tid = threadIdx.x, lane = tid & 63, wv = tid >> 6;   // wv 0..7
  const int lrow = lane >> 2, lchunk = lane & 3;
  // A staging: wave wv owns rows [wv*32, wv*32+32) (2 instrs of 16 rows per chunk)
  const bf16* ga = A + (long)(m0 + wv*32 + lrow)*lda + lchunk*8;
  // B staging: wave wv owns rows [wv*16, wv*16+16) (1 instr per chunk)
  const bf16* gb = Bt + (long)(n0 + wv*16 + lrow)*ldb + lchunk*8;
  bf16* lA = As + (wv*32)*32;
  bf16* lB = Bs + (wv*16)*32;
  // wave quadrant: 4 rows x 2 cols of 64x64
  const int mBase = (wv >> 1)*64, nBase = (wv & 1)*64;
  const int fr = lane & 15, fq = lane >> 4;

  f32x4 acc[4][4];
  #pragma unroll
  for (int i = 0; i < 4; i++)
    #pragma unroll
    for (int j = 0; j < 4; j++) acc[i][j] = (f32x4){0.f,0.f,0.f,0.f};

  const int nk = K >> 6;   // BK=64; all call sites have K % 64 == 0
  for (int t = 0; t < nk; ++t) {
    const int k0 = t << 6;
    #pragma unroll
    for (int c = 0; c < 2; c++) {
      gl_lds16(ga + k0 + c*32,          lA + c*CHA);
      gl_lds16(ga + k0 + c*32 + 16*lda, lA + c*CHA + 16*32);
      gl_lds16(gb + k0 + c*32,          lB + c*CHB);
    }
    asm volatile("s_waitcnt vmcnt(0)" ::: "memory");
    __syncthreads();
    #pragma unroll
    for (int c = 0; c < 2; c++) {
      const bf16* Ab = As + c*CHA;
      const bf16* Bb = Bs + c*CHB;
      bf16x8 af[4], bfr[4];
      #pragma unroll
      for (int mi = 0; mi < 4; mi++)
        af[mi] = *(const bf16x8*)(Ab + (mBase + mi*16 + fr)*32 + fq*8);
      #pragma unroll
      for (int ni = 0; ni < 4; ni++)
        bfr[ni] = *(const bf16x8*)(Bb + (nBase + ni*16 + fr)*32 + fq*8);
      #pragma unroll
      for (int mi = 0; mi < 4; mi++)
        #pragma unroll
        for (int ni = 0; ni < 4; ni++)
          acc[mi][ni] = __builtin_amdgcn_mfma_f32_16x16x32_bf16(af[mi], bfr[ni], acc[mi][ni], 0, 0, 0);
    }
    __syncthreads();
  }

  #pragma unroll
  for (int mi = 0; mi < 4; mi++)
    #pragma unroll
    for (int ni = 0; ni < 4; ni++)
      #pragma unroll
      for (int r = 0; r < 4; r++) {
        int gm = m0 + mBase + mi*16 + fq*4 + r;
        int gn = n0 + nBase + ni*16 + fr;
        if (gm >= Mb || gn >= Nb) continue;
        float v = acc[mi][ni][r] * alpha;
        if (mode == 0) {
          if (bias) v += bias[gn];
          if (resb) v += __bfloat162float(resb[(long)z*resStride + (long)gm*ldc + gn]);
          Cf[(long)z*cStride + (long)gm*ldc + gn] = v;
        } else {
          Cb[(long)z*cStride + (long)gm*ldc + gn] = __float2bfloat16(v);
        }
      }
}

// ================= AV GEMM: x[z] = Apad[z] @ Gt[z]^T + xnb[z], full-K staging =================
// 64x64 tile, K=224 staged entirely in LDS (56 KB -> 2 blocks/CU for cross-block overlap;
// r10 showed the 128^2 / 112 KB / 1-block-per-CU variant serializes and regresses).
// One drain, 28 MFMAs barrier-free.
__global__ __launch_bounds__(256) void gemm_av(
    const bf16* __restrict__ Apad, const bf16* __restrict__ Gt,
    const bf16* __restrict__ resb, float* __restrict__ Cf) {
  __shared__ __align__(16) bf16 As[7*64*32];   // 28 KB
  __shared__ __align__(16) bf16 Bs[7*64*32];   // 28 KB
  const int CH = 64*32;
  int bx, by, bz;
  xcd_swizzle(bx, by, bz);
  const int z = bz, m0 = by*64, n0 = bx*64;
  const int tid = threadIdx.x, lane = tid & 63, wv = tid >> 6;
  const int lrow = lane >> 2, lchunk = lane & 3;
  // each wave stages 16 rows of A and 16 rows of B per 32-col chunk (1 KB/instr)
  const bf16* ga = Apad + ((long)z*APAD_R + m0 + wv*16 + lrow)*APAD_C + lchunk*8;
  const bf16* gb = Gt   + ((long)z*DIMD  + n0 + wv*16 + lrow)*APAD_C + lchunk*8;
  bf16* lA = As + (wv*16)*32;
  bf16* lB = Bs + (wv*16)*32;
  #pragma unroll
  for (int c = 0; c < 7; c++) {
    gl_lds16(ga + c*32, lA + c*CH);
    gl_lds16(gb + c*32, lB + c*CH);
  }
  asm volatile("s_waitcnt vmcnt(0)" ::: "memory");
  __syncthreads();

  // wave (wr,wc) owns a 32x32 quadrant of the 64x64 tile
  const int mBase = (wv >> 1)*32, nBase = (wv & 1)*32;
  const int fr = lane & 15, fq = lane >> 4;
  f32x4 acc[2][2];
  #pragma unroll
  for (int i = 0; i < 2; i++)
    #pragma unroll
    for (int j = 0; j < 2; j++) acc[i][j] = (f32x4){0.f,0.f,0.f,0.f};

  #pragma unroll
  for (int c = 0; c < 7; c++) {
    const bf16* Ab = As + c*CH;
    const bf16* Bb = Bs + c*CH;
    bf16x8 af[2], bfr[2];
    #pragma unroll
    for (int mi = 0; mi < 2; mi++)
      af[mi] = *(const bf16x8*)(Ab + (mBase + mi*16 + fr)*32 + fq*8);
    #pragma unroll
    for (int ni = 0; ni < 2; ni++)
      bfr[ni] = *(const bf16x8*)(Bb + (nBase + ni*16 + fr)*32 + fq*8);
    #pragma unroll
    for (int mi = 0; mi < 2; mi++)
      #pragma unroll
      for (int ni = 0; ni < 2; ni++)
        acc[mi][ni] = __builtin_amdgcn_mfma_f32_16x16x32_bf16(af[mi], bfr[ni], acc[mi][ni], 0, 0, 0);
  }

  #pragma unroll
  for (int mi = 0; mi < 2; mi++)
    #pragma unroll
    for (int ni = 0; ni < 2; ni++)
      #pragma unroll
      for (int r = 0; r < 4; r++) {
        int gm = m0 + mBase + mi*16 + fq*4 + r;
        int gn = n0 + nBase + ni*16 + fr;
        if (gm >= NTOK) continue;
        float v = acc[mi][ni][r]
                + __bfloat162float(resb[(long)z*NTOK*DIMD + (long)gm*DIMD + gn]);
        Cf[(long)z*NTOK*DIMD + (long)gm*DIMD + gn] = v;
      }
}

// ====== fused QKT+softmax: per batch z, 64-row tile x full 224-col width ======
// logits = xm[z] @ xnb[z]^T (fp32 acc), row-softmax with max-sub, writes bf16 Apad.
// Depth-3 ring pipeline (1 block/CU -> prefetch is the only latency hiding).
__global__ __launch_bounds__(256) void gemm_qs(
    const bf16* __restrict__ xmp, const bf16* __restrict__ xnbp,
    bf16* __restrict__ Apad, float scale) {
  __shared__ __align__(16) bf16 As[3][64*32];
  __shared__ __align__(16) bf16 Bs[3][224*32];
  const int ABUF = 64*32, BBUF = 224*32;
  int bx, by, bz;
  xcd_swizzle(bx, by, bz);
  const int z = bz;
  const int y0 = by*64;                         // 0,64,128,192
  const bf16* A  = xmp  + (long)z*NTOK*DIMD;
  const bf16* Bt = xnbp + (long)z*NTOK*DIMD;
  const int tid = threadIdx.x, lane = tid & 63, wv = tid >> 6;
  const int lrow = lane >> 2, lchunk = lane & 3;
  const bf16* ga = A + (long)(y0 + wv*16 + lrow)*DIMD + lchunk*8;
  bf16* lA = &As[0][(wv*16)*32];
  const bf16* gb = Bt + (long)(wv*64 + lrow)*DIMD + lchunk*8;
  bf16* lB = &Bs[0][(wv*64)*32];
  const int nIss = (wv < 3) ? 4 : 2;            // per-wave B issues (+1 A issue)
  const int fr = lane & 15, fq = lane >> 4;

  f32x4 acc[14];
  #pragma unroll
  for (int j = 0; j < 14; j++) acc[j] = (f32x4){0.f,0.f,0.f,0.f};

  const int nk = 32;
  // prologue: stage tiles 0 and 1
  #pragma unroll
  for (int p = 0; p < 2; p++) {
    gl_lds16(ga + p*32, lA + p*ABUF);
    for (int i = 0; i < nIss; i++)
      gl_lds16(gb + p*32 + (long)i*16*DIMD, lB + p*BBUF + i*16*32);
  }
  for (int t = 0; t < nk; ++t) {
    const int cur = t % 3;
    if (t + 2 < nk) {
      const int nb = (t + 2) % 3;
      const int k2 = (t + 2) << 5;
      gl_lds16(ga + k2, lA + nb*ABUF);
      for (int i = 0; i < nIss; i++)
        gl_lds16(gb + k2 + (long)i*16*DIMD, lB + nb*BBUF + i*16*32);
    }
    const int ahead = (nk - 1 - t > 2) ? 2 : (nk - 1 - t);
    if (wv < 3) {      // 5 loads/stage
      if (ahead == 2)      asm volatile("s_waitcnt vmcnt(10)" ::: "memory");
      else if (ahead == 1) asm volatile("s_waitcnt vmcnt(5)"  ::: "memory");
      else                 asm volatile("s_waitcnt vmcnt(0)"  ::: "memory");
    } else {           // 3 loads/stage
      if (ahead == 2)      asm volatile("s_waitcnt vmcnt(6)"  ::: "memory");
      else if (ahead == 1) asm volatile("s_waitcnt vmcnt(3)"  ::: "memory");
      else                 asm volatile("s_waitcnt vmcnt(0)"  ::: "memory");
    }
    __builtin_amdgcn_s_barrier();
    const bf16* Ab = &As[cur][0];
    const bf16* Bb = &Bs[cur][0];
    bf16x8 af = *(const bf16x8*)(Ab + (wv*16 + fr)*32 + fq*8);
    #pragma unroll
    for (int j = 0; j < 14; j++) {
      bf16x8 bfr = *(const bf16x8*)(Bb + (j*16 + fr)*32 + fq*8);
      acc[j] = __builtin_amdgcn_mfma_f32_16x16x32_bf16(af, bfr, acc[j], 0, 0, 0);
    }
    asm volatile("s_waitcnt lgkmcnt(0)" ::: "memory");
    __builtin_amdgcn_s_barrier();
  }

  // per-row softmax: row = y0 + wv*16 + fq*4 + r; cols j*16 + fr
  #pragma unroll
  for (int r = 0; r < 4; r++) {
    float mx = -INFINITY;
    #pragma unroll
    for (int j = 0; j < 14; j++) {
      int col = j*16 + fr;
      if (col < NTOK) mx = fmaxf(mx, acc[j][r]);
    }
    #pragma unroll
    for (int off = 1; off < 16; off <<= 1) mx = fmaxf(mx, __shfl_xor(mx, off));
    float e[14];
    float s = 0.f;
    #pragma unroll
    for (int j = 0; j < 14; j++) {
      int col = j*16 + fr;
      e[j] = (col < NTOK) ? __expf((acc[j][r] - mx) * scale) : 0.f;
      s += e[j];
    }
    #pragma unroll
    for (int off = 1; off < 16; off <<= 1) s += __shfl_xor(s, off);
    float inv = 1.f / s;
    int grow = y0 + wv*16 + fq*4 + r;
    bf16* dst = Apad + ((long)z*APAD_R + grow)*APAD_C;
    #pragma unroll
    for (int j = 0; j < 14; j++) {
      int col = j*16 + fr;
      float outv = (grow < NTOK) ? e[j]*inv : 0.f;   // col>=196 -> e=0 -> writes 0
      dst[col] = __float2bfloat16(outv);
    }
  }
}

// ====== V-GEMM direct-Gt: Gt[z][h*128+d][t] = sum_e WVt[d][e]*xnb[z*196+t][h*128+e] ======
// K=128: stage the ENTIRE K up front (4 chunks), one drain, then barrier-free MFMA loop.
__global__ __launch_bounds__(256) void gemm_v(
    const bf16* __restrict__ WVt, const bf16* __restrict__ xnb, bf16* __restrict__ Gt) {
  __shared__ __align__(16) bf16 As[4][128*32];   // 32 KB
  __shared__ __align__(16) bf16 Bs[4][128*32];   // 32 KB
  const int CH = 128*32;
  int bx, by, bz;
  xcd_swizzle(bx, by, bz);
  const int z = bz, h = by, n0 = bx*128;
  const int tid = threadIdx.x, lane = tid & 63, wv = tid >> 6;
  const int lrow = lane >> 2, lchunk = lane & 3;
  const bf16* ga = WVt + (long)(wv*32 + lrow)*HD + lchunk*8;
  const bf16* gb = xnb + (long)(z*NTOK + n0 + wv*32 + lrow)*DIMD + h*HD + lchunk*8;
  bf16* lA = &As[0][(wv*32)*32];
  bf16* lB = &Bs[0][(wv*32)*32];
  const int mBase = (wv & 1)*64, nBase = (wv >> 1)*64;
  const int fr = lane & 15, fq = lane >> 4;

  f32x4 acc[4][4];
  #pragma unroll
  for (int i = 0; i < 4; i++)
    #pragma unroll
    for (int j = 0; j < 4; j++) acc[i][j] = (f32x4){0.f,0.f,0.f,0.f};

  #pragma unroll
  for (int c = 0; c < 4; c++) {
    gl_lds16(ga + c*32,           lA + c*CH);
    gl_lds16(ga + c*32 + 16*HD,   lA + c*CH + 16*32);
    gl_lds16(gb + c*32,           lB + c*CH);
    gl_lds16(gb + c*32 + 16*DIMD, lB + c*CH + 16*32);
  }
  asm volatile("s_waitcnt vmcnt(0)" ::: "memory");
  __syncthreads();

  #pragma unroll
  for (int c = 0; c < 4; c++) {
    const bf16* Ab = &As[c][0];
    const bf16* Bb = &Bs[c][0];
    bf16x8 af[4], bfr[4];
    #pragma unroll
    for (int mi = 0; mi < 4; mi++)
      af[mi] = *(const bf16x8*)(Ab + (mBase + mi*16 + fr)*32 + fq*8);
    #pragma unroll
    for (int ni = 0; ni < 4; ni++)
      bfr[ni] = *(const bf16x8*)(Bb + (nBase + ni*16 + fr)*32 + fq*8);
    #pragma unroll
    for (int mi = 0; mi < 4; mi++)
      #pragma unroll
      for (int ni = 0; ni < 4; ni++)
        acc[mi][ni] = __builtin_amdgcn_mfma_f32_16x16x32_bf16(af[mi], bfr[ni], acc[mi][ni], 0, 0, 0);
  }

  #pragma unroll
  for (int mi = 0; mi < 4; mi++)
    #pragma unroll
    for (int ni = 0; ni < 4; ni++)
      #pragma unroll
      for (int r = 0; r < 4; r++) {
        int gm = mBase + mi*16 + fq*4 + r;          // output dim within head (0..127)
        int gn = n0 + nBase + ni*16 + fr;           // token
        if (gn < NTOK)
          Gt[((long)z*DIMD + h*HD + gm)*APAD_C + gn] = __float2bfloat16(acc[mi][ni][r]);
        else if (gn < APAD_C)
          Gt[((long)z*DIMD + h*HD + gm)*APAD_C + gn] = __float2bfloat16(0.f);
      }
}

// ================= classifier split-K (K=128: full up-front staging) =================
__global__ __launch_bounds__(256) void gemm_cls(
    const bf16* __restrict__ A, const bf16* __restrict__ Bt,
    float* __restrict__ Cp) {
  __shared__ __align__(16) bf16 As[4][64*32];    // 16 KB
  __shared__ __align__(16) bf16 Bs[4][128*32];   // 32 KB
  const int ACH = 64*32, BCH = 128*32;
  const int n0 = blockIdx.x*128, kz = blockIdx.y;
  const int tid = threadIdx.x, lane = tid & 63, wv = tid >> 6;
  const bf16* ga = A + (tid>>2)*DIMD + kz*128 + (tid&3)*8;
  const bf16* gb = Bt + (long)(n0 + wv*32 + (lane>>2))*DIMD + kz*128 + (lane&3)*8;
  bf16* lA = &As[0][wv*512];
  bf16* lB = &Bs[0][(wv*32)*32];
  const int fr = lane & 15, fq = lane >> 4;
  f32x4 acc[4][2];
  #pragma unroll
  for (int i = 0; i < 4; i++)
    #pragma unroll
    for (int j = 0; j < 2; j++) acc[i][j] = (f32x4){0.f,0.f,0.f,0.f};
  #pragma unroll
  for (int it = 0; it < 4; it++) {
    gl_lds16(ga + it*32, lA + it*ACH);
    gl_lds16(gb + it*32,            lB + it*BCH);
    gl_lds16(gb + it*32 + 16*DIMD,  lB + it*BCH + 16*32);
  }
  asm volatile("s_waitcnt vmcnt(0)" ::: "memory");
  __syncthreads();
  #pragma unroll
  for (int it = 0; it < 4; it++) {
    const bf16* Ab = &As[it][0];
    const bf16* Bb = &Bs[it][0];
    bf16x8 af[4], bfr[2];
    #pragma unroll
    for (int mi = 0; mi < 4; mi++)
      af[mi] = *(const bf16x8*)(Ab + (mi*16 + fr)*32 + fq*8);
    #pragma unroll
    for (int ni = 0; ni < 2; ni++)
      bfr[ni] = *(const bf16x8*)(Bb + (wv*32 + ni*16 + fr)*32 + fq*8);
    #pragma unroll
    for (int mi = 0; mi < 4; mi++)
      #pragma unroll
      for (int ni = 0; ni < 2; ni++)
        acc[mi][ni] = __builtin_amdgcn_mfma_f32_16x16x32_bf16(af[mi], bfr[ni], acc[mi][ni], 0, 0, 0);
  }
  #pragma unroll
  for (int mi = 0; mi < 4; mi++)
    #pragma unroll
    for (int ni = 0; ni < 2; ni++)
      #pragma unroll
      for (int r = 0; r < 4; r++) {
        int gm = mi*16 + fq*4 + r;
        int gn = n0 + wv*32 + ni*16 + fr;
        Cp[((long)kz*64 + gm)*DIMD + gn] = acc[mi][ni][r];
      }
}

__global__ __launch_bounds__(256) void cls_reduce(
    const float* __restrict__ Cp, const float* __restrict__ bias,
    float* __restrict__ out) {
  int i = blockIdx.x*256 + threadIdx.x;
  int m = i / 1000, n = i - m*1000;
  float s = bias[n];
  #pragma unroll
  for (int kz = 0; kz < 8; kz++) s += Cp[((long)kz*64 + m)*DIMD + n];
  out[i] = s;
}

// ================= patchify + LN1 (dim 768) -> bf16 =================
__global__ __launch_bounds__(256) void patchify_ln(
    const float* __restrict__ img, const float* __restrict__ g,
    const float* __restrict__ b, bf16* __restrict__ out) {
  int t = blockIdx.x;
  int bi = t / NTOK, n = t % NTOK;
  int ph = n / 14, pw = n % 14;
  __shared__ float vals[PD];
  __shared__ float part[8];
  int tid = threadIdx.x;
  int lane = tid & 63, wv = tid >> 6;
  for (int j = tid; j < PD; j += 256) {
    int p1 = j / 48, rem = j % 48, p2 = rem / 3, c = rem % 3;
    vals[j] = img[(((long)bi*3 + c)*224 + (ph*16 + p1))*224 + (pw*16 + p2)];
  }
  __syncthreads();
  float s = 0.f;
  for (int j = tid; j < PD; j += 256) s += vals[j];
  #pragma unroll
  for (int off = 1; off < 64; off <<= 1) s += __shfl_xor(s, off);
  if (lane == 0) part[wv] = s;
  __syncthreads();
  float mean = (part[0]+part[1]+part[2]+part[3]) / (float)PD;
  float s2 = 0.f;
  for (int j = tid; j < PD; j += 256) { float d = vals[j]-mean; s2 += d*d; }
  #pragma unroll
  for (int off = 1; off < 64; off <<= 1) s2 += __shfl_xor(s2, off);
  if (lane == 0) part[4+wv] = s2;
  __syncthreads();
  float rstd = rsqrtf((part[4]+part[5]+part[6]+part[7])/(float)PD + LN_EPS);
  for (int j = tid; j < PD; j += 256)
    out[(long)t*PD + j] = __float2bfloat16((vals[j]-mean)*rstd*g[j] + b[j]);
}

// ================= LayerNorm rows (dim=1024): optional fp32 out, optional bf16 out =================
__global__ __launch_bounds__(256) void ln_rows2(
    const float* __restrict__ in, const float* __restrict__ g,
    const float* __restrict__ b, const float* __restrict__ pos,
    float* __restrict__ outf, ushort4* __restrict__ outb) {
  long t = blockIdx.x;
  int tid = threadIdx.x;
  int lane = tid & 63, wv = tid >> 6;
  float4 v = ((const float4*)(in + t*DIMD))[tid];
  float s  = v.x+v.y+v.z+v.w;
  float s2 = v.x*v.x+v.y*v.y+v.z*v.z+v.w*v.w;
  #pragma unroll
  for (int off = 1; off < 64; off <<= 1) {
    s  += __shfl_xor(s, off);
    s2 += __shfl_xor(s2, off);
  }
  __shared__ float ps[4], pq[4];
  if (lane == 0) { ps[wv] = s; pq[wv] = s2; }
  __syncthreads();
  s  = ps[0]+ps[1]+ps[2]+ps[3];
  s2 = pq[0]+pq[1]+pq[2]+pq[3];
  float mean = s*(1.f/1024.f);
  float var  = s2*(1.f/1024.f) - mean*mean;
  float rstd = rsqrtf(var + LN_EPS);
  float4 gg = ((const float4*)g)[tid];
  float4 bb = ((const float4*)b)[tid];
  float4 o;
  o.x = (v.x-mean)*rstd*gg.x + bb.x;
  o.y = (v.y-mean)*rstd*gg.y + bb.y;
  o.z = (v.z-mean)*rstd*gg.z + bb.z;
  o.w = (v.w-mean)*rstd*gg.w + bb.w;
  if (pos) {
    float4 pp = ((const float4*)(pos + (long)(t % NTOK)*DIMD))[tid];
    o.x += pp.x; o.y += pp.y; o.z += pp.z; o.w += pp.w;
  }
  if (outf) ((float4*)(outf + t*DIMD))[tid] = o;
  if (outb) {
    ushort4 u;
    u.x = bfbits(o.x); u.y = bfbits(o.y); u.z = bfbits(o.z); u.w = bfbits(o.w);
    outb[t*256 + tid] = u;
  }
}

// ================= cast + transpose weights: fp32 [R][C] -> bf16 [C][R] =================
__global__ void castT(const float* __restrict__ src, bf16* __restrict__ dst, int R, int C) {
  __shared__ float t[32][33];
  int rb = blockIdx.y*32, cb = blockIdx.x*32;
  int tx = threadIdx.x, ty = threadIdx.y;  // (32,8)
  for (int i = ty; i < 32; i += 8)
    if (rb+i < R && cb+tx < C) t[i][tx] = src[(long)(rb+i)*C + cb+tx];
  __syncthreads();
  for (int i = ty; i < 32; i += 8)
    if (cb+i < C && rb+tx < R) dst[(long)(cb+i)*R + rb+tx] = __float2bfloat16(t[tx][i]);
}

// ================= natural cast fp32 -> bf16 (elementwise, float4) =================
__global__ __launch_bounds__(256) void castN(
    const float* __restrict__ src, ushort4* __restrict__ dst) {
  int i = blockIdx.x*256 + threadIdx.x;
  float4 v = ((const float4*)src)[i];
  ushort4 u;
  u.x = bfbits(v.x); u.y = bfbits(v.y); u.z = bfbits(v.z); u.w = bfbits(v.w);
  dst[i] = u;
}

// ================= mean over tokens -> bf16 =================
__global__ __launch_bounds__(256) void mean_tokens(
    const float* __restrict__ x, bf16* __restrict__ outb) {
  int b = blockIdx.x;
  int d = blockIdx.y*256 + threadIdx.x;
  const float* p = x + (long)b*NTOK*DIMD + d;
  float s = 0.f;
  #pragma unroll 4
  for (int n = 0; n < NTOK; n++) s += p[(long)n*DIMD];
  outb[(long)b*DIMD + d] = __float2bfloat16(s * (1.f/196.f));
}

extern "C" void kernel_launch(void* const* d_in, const int* in_sizes, int n_in,
                              void* d_out, int out_size, void* d_ws, size_t ws_size,
                              hipStream_t stream) {
  (void)in_sizes; (void)n_in; (void)out_size; (void)ws_size;
  const float* image = (const float*)d_in[0];
  const float* ln1_g = (const float*)d_in[1];
  const float* ln1_b = (const float*)d_in[2];
  const float* W_emb = (const float*)d_in[3];
  const float* b_emb = (const float*)d_in[4];
  const float* ln2_g = (const float*)d_in[5];
  const float* ln2_b = (const float*)d_in[6];
  const float* pos   = (const float*)d_in[7];
  const float* norm_g= (const float*)d_in[8];
  const float* norm_b= (const float*)d_in[9];
  const float* WV    = (const float*)d_in[10];
  const float* WK    = (const float*)d_in[11];
  const float* WQ    = (const float*)d_in[12];
  const float* lastW = (const float*)d_in[13];
  const float* lastb = (const float*)d_in[14];
  float* out = (float*)d_out;

  char* W = (char*)d_ws;
  float* x     = (float*)(W);                      // 51,380,224
  bf16*  xnb   = (bf16*) (W + 51380224);           // 25,690,112
  bf16*  xm    = (bf16*) (W + 77070336);           // 25.7MB in 51.6MB slab (alias Xp; overread zone)
  bf16*  Xp    = xm;
  // slabB: embed-phase xn (fp32 51.4 MB) OR layer-phase Gt+Apad
  float* xn    = (float*)(W + 128712704);
  bf16*  Gt    = (bf16*) (W + 128712704);          // 29,360,128
  bf16*  Apad  = (bf16*) (W + 167907328);          //  7,340,032
  bf16*  WembT = (bf16*) (W + 180092928);          //  1,572,864
  bf16*  WQb   = (bf16*) (W + 181665792);          //  2,097,152 (natural layout)
  bf16*  WKb   = (bf16*) (W + 183762944);          //  2,097,152 (natural layout)
  bf16*  WVt   = (bf16*) (W + 185860096);          //     32,768
  bf16*  lastWT= (bf16*) (W + 185892864);          //  2,097,152
  bf16*  meanxb= (bf16*) (W + 187990016);          //    131,072
  float* clsPart=(float*)(W + 188121088);          //  2,097,152
  bf16*  Mt    = (bf16*) (W + 190218240);          //  2,097,152 (M^T = WK @ WQ^T)

  dim3 blk(256);
  dim3 blk512(512);
  const float scale = 0.08838834764831845f;  // 128^-0.5
  const long ZR = 0;

  // weight casts
  castT<<<dim3(32, 24), dim3(32, 8), 0, stream>>>(W_emb, WembT, PD, DIMD);
  castN<<<1024, blk, 0, stream>>>(WQ, (ushort4*)WQb);
  castN<<<1024, blk, 0, stream>>>(WK, (ushort4*)WKb);
  castT<<<dim3(4, 4),  dim3(32, 8), 0, stream>>>(WV, WVt, HD, HD);
  castT<<<dim3(32, 32), dim3(32, 8), 0, stream>>>(lastW, lastWT, DIMD, 1000);
  // Mt[j][i] = sum_k WK[j][k]*WQ[i][k]  (= (WQ @ WK^T)^T); M=1024 -> 4 x 256-row tiles
  gemm_mfma<<<dim3(8, 4, 1), blk512, 0, stream>>>(
      WKb, DIMD, ZR, WQb, DIMD, ZR, DIMD, 1,
      nullptr, Mt, DIMD, ZR, nullptr, nullptr, ZR, 1.f, DIMD, DIMD);

  // patch embed  (M=12544 = 49 x 256 exactly)
  patchify_ln<<<TOKENS, blk, 0, stream>>>(image, ln1_g, ln1_b, Xp);
  gemm_mfma<<<dim3(8, 49, 1), blk512, 0, stream>>>(
      Xp, PD, ZR, WembT, PD, ZR, PD, 0,
      xn, nullptr, DIMD, ZR, b_emb, nullptr, ZR, 1.f, TOKENS, DIMD);
  ln_rows2<<<TOKENS, blk, 0, stream>>>(xn, ln2_g, ln2_b, pos, x, nullptr);

  for (int l = 0; l < DEPTH; l++) {
    // xnb = bf16(LN(x))
    ln_rows2<<<TOKENS, blk, 0, stream>>>(x, norm_g, norm_b, nullptr, nullptr, (ushort4*)xnb);
    // xm = xnb @ M
    gemm_mfma<<<dim3(8, 49, 1), blk512, 0, stream>>>(
        xnb, DIMD, ZR, Mt, DIMD, ZR, DIMD, 1,
        nullptr, xm, DIMD, ZR, nullptr, nullptr, ZR, 1.f, TOKENS, DIMD);
    // Apad = softmax(xm @ xnb^T * scale), fused, pads zeroed
    gemm_qs<<<dim3(1, 4, BATCH), blk, 0, stream>>>(xm, xnb, Apad, scale);
    // Gt[b][dim][tok] = WV^T @ xn^T  (direct transposed layout, pad cols zeroed)
    gemm_v<<<dim3(2, HEADS, BATCH), blk, 0, stream>>>(WVt, xnb, Gt);
    // x = Apad @ G + xnb (bf16 residual), full-K staged, 64x64 tiles (2 blocks/CU)
    gemm_av<<<dim3(16, 4, BATCH), blk, 0, stream>>>(Apad, Gt, xnb, x);
  }

  // classifier
  mean_tokens<<<dim3(BATCH, 4), blk, 0, stream>>>(x, meanxb);
  gemm_cls<<<dim3(8, 8), blk, 0, stream>>>(meanxb, lastWT, clsPart);
  cls_reduce<<<250, blk, 0, stream>>>(clsPart, lastb, out);
}

// Round 12
// 1052.014 us; speedup vs baseline: 1.2406x; 1.0613x over previous
//
#include <hip/hip_runtime.h>
#include <hip/hip_bf16.h>
#include <math.h>

#define NTOK   196
#define BATCH  64
#define TOKENS (BATCH*NTOK)   // 12544
#define DIMD   1024
#define PD     768
#define HEADS  8
#define HD     128
#define DEPTH  6
#define LN_EPS 1e-5f
#define APAD_R 256            // padded A rows per batch (for 256-row tiles)
#define APAD_C 256            // padded K dim for A@G (4*64; cols 196..256 zeroed)

typedef __hip_bfloat16 bf16;
typedef __attribute__((ext_vector_type(8))) short bf16x8;
typedef __attribute__((ext_vector_type(4))) float f32x4;

typedef const __attribute__((address_space(1))) void* gptr_t;
typedef __attribute__((address_space(3))) void* lptr_t;

__device__ __forceinline__ void gl_lds16(const bf16* g, bf16* l) {
  __builtin_amdgcn_global_load_lds((gptr_t)(const void*)g, (lptr_t)(void*)l, 16, 0, 0);
}
__device__ __forceinline__ unsigned short bfbits(float f) {
  bf16 h = __float2bfloat16(f);
  return *(unsigned short*)&h;
}

// XCD-aware bijective swizzle (requires nwg % 8 == 0, true for all call sites):
// physical block f runs work item (f%8)*(nwg/8) + f/8, so each XCD gets a
// CONTIGUOUS range of work ids -> operand-panel-sharing blocks co-locate on one L2.
__device__ __forceinline__ void xcd_swizzle(int& bx, int& by, int& bz) {
  const int gx = gridDim.x, gy = gridDim.y;
  const int nwg = gx*gy*gridDim.z;
  const int flat = blockIdx.x + gx*(blockIdx.y + gy*blockIdx.z);
  const int swz = (flat & 7)*(nwg >> 3) + (flat >> 3);
  bx = swz % gx;
  const int rest = swz / gx;
  by = rest % gy;
  bz = rest / gy;
}

// ================= generic MFMA GEMM: C[m][n] = sum_k A[m][k] * Bt[n][k] =================
// 256x128 tile, 512 threads (8 waves, each a 64x64 quadrant: 4 rows x 2 cols of waves),
// BK=64 (two [.][32] chunks per barrier pair). Measured r11: staging service ~6 TB/s
// at this shape (vs 2.5 TB/s for the 128^2 tile) -> xm 63.5 -> <52 us. Single LDS
// buffer 48 KB -> 2-3 blocks/CU. K-accumulation order per fragment unchanged ->
// bit-identical output. mode 0: Cf = acc*alpha (+bias)(+bf16 res); mode 1: Cb = bf16
__global__ __launch_bounds__(512) void gemm_mfma(
    const bf16* __restrict__ A, int lda, long aStride,
    const bf16* __restrict__ Bt, int ldb, long bStride,
    int K, int mode,
    float* __restrict__ Cf, bf16* __restrict__ Cb, int ldc, long cStride,
    const float* __restrict__ bias, const bf16* __restrict__ resb, long resStride,
    float alpha, int Mb, int Nb) {
  __shared__ __align__(16) bf16 As[2*256*32];   // 32 KB (2 chunks x 256 rows x 32 cols)
  __shared__ __align__(16) bf16 Bs[2*128*32];   // 16 KB
  const int CHA = 256*32, CHB = 128*32;
  int bx, by, bz;
  xcd_swizzle(bx, by, bz);
  const int z = bz;
  A  += (long)z*aStride;
  Bt += (long)z*bStride;
  const int m0 = by*256, n0 = bx*128;
  const int tid = threadIdx.x, lane = tid & 63, wv = tid >> 6;   // wv 0..7
  const int lrow = lane >> 2, lchunk = lane & 3;
  // A staging: wave wv owns rows [wv*32, wv*32+32) (2 instrs of 16 rows per chunk)
  const bf16* ga = A + (long)(m0 + wv*32 + lrow)*lda + lchunk*8;
  // B staging: wave wv owns rows [wv*16, wv*16+16) (1 instr per chunk)
  const bf16* gb = Bt + (long)(n0 + wv*16 + lrow)*ldb + lchunk*8;
  bf16* lA = As + (wv*32)*32;
  bf16* lB = Bs + (wv*16)*32;
  // wave quadrant: 4 rows x 2 cols of 64x64
  const int mBase = (wv >> 1)*64, nBase = (wv & 1)*64;
  const int fr = lane & 15, fq = lane >> 4;

  f32x4 acc[4][4];
  #pragma unroll
  for (int i = 0; i < 4; i++)
    #pragma unroll
    for (int j = 0; j < 4; j++) acc[i][j] = (f32x4){0.f,0.f,0.f,0.f};

  const int nk = K >> 6;   // BK=64; all call sites have K % 64 == 0
  for (int t = 0; t < nk; ++t) {
    const int k0 = t << 6;
    #pragma unroll
    for (int c = 0; c < 2; c++) {
      gl_lds16(ga + k0 + c*32,          lA + c*CHA);
      gl_lds16(ga + k0 + c*32 + 16*lda, lA + c*CHA + 16*32);
      gl_lds16(gb + k0 + c*32,          lB + c*CHB);
    }
    asm volatile("s_waitcnt vmcnt(0)" ::: "memory");
    __syncthreads();
    #pragma unroll
    for (int c = 0; c < 2; c++) {
      const bf16* Ab = As + c*CHA;
      const bf16* Bb = Bs + c*CHB;
      bf16x8 af[4], bfr[4];
      #pragma unroll
      for (int mi = 0; mi < 4; mi++)
        af[mi] = *(const bf16x8*)(Ab + (mBase + mi*16 + fr)*32 + fq*8);
      #pragma unroll
      for (int ni = 0; ni < 4; ni++)
        bfr[ni] = *(const bf16x8*)(Bb + (nBase + ni*16 + fr)*32 + fq*8);
      #pragma unroll
      for (int mi = 0; mi < 4; mi++)
        #pragma unroll
        for (int ni = 0; ni < 4; ni++)
          acc[mi][ni] = __builtin_amdgcn_mfma_f32_16x16x32_bf16(af[mi], bfr[ni], acc[mi][ni], 0, 0, 0);
    }
    __syncthreads();
  }

  #pragma unroll
  for (int mi = 0; mi < 4; mi++)
    #pragma unroll
    for (int ni = 0; ni < 4; ni++)
      #pragma unroll
      for (int r = 0; r < 4; r++) {
        int gm = m0 + mBase + mi*16 + fq*4 + r;
        int gn = n0 + nBase + ni*16 + fr;
        if (gm >= Mb || gn >= Nb) continue;
        float v = acc[mi][ni][r] * alpha;
        if (mode == 0) {
          if (bias) v += bias[gn];
          if (resb) v += __bfloat162float(resb[(long)z*resStride + (long)gm*ldc + gn]);
          Cf[(long)z*cStride + (long)gm*ldc + gn] = v;
        } else {
          Cb[(long)z*cStride + (long)gm*ldc + gn] = __float2bfloat16(v);
        }
      }
}

// ====== fused QKT+softmax: per batch z, 64-row tile x full 224-col width ======
// logits = xm[z] @ xnb[z]^T (fp32 acc), row-softmax with max-sub, writes bf16 Apad
// (stride APAD_C=256; cols [224,256) zero-filled so the padded-K AV GEMM sees no
// garbage -- Gt cols [196,256) are also zero, so padded products are exactly 0).
// Depth-3 ring pipeline (1 block/CU -> prefetch is the only latency hiding).
__global__ __launch_bounds__(256) void gemm_qs(
    const bf16* __restrict__ xmp, const bf16* __restrict__ xnbp,
    bf16* __restrict__ Apad, float scale) {
  __shared__ __align__(16) bf16 As[3][64*32];
  __shared__ __align__(16) bf16 Bs[3][224*32];
  const int ABUF = 64*32, BBUF = 224*32;
  int bx, by, bz;
  xcd_swizzle(bx, by, bz);
  const int z = bz;
  const int y0 = by*64;                         // 0,64,128,192
  const bf16* A  = xmp  + (long)z*NTOK*DIMD;
  const bf16* Bt = xnbp + (long)z*NTOK*DIMD;
  const int tid = threadIdx.x, lane = tid & 63, wv = tid >> 6;
  const int lrow = lane >> 2, lchunk = lane & 3;
  const bf16* ga = A + (long)(y0 + wv*16 + lrow)*DIMD + lchunk*8;
  bf16* lA = &As[0][(wv*16)*32];
  const bf16* gb = Bt + (long)(wv*64 + lrow)*DIMD + lchunk*8;
  bf16* lB = &Bs[0][(wv*64)*32];
  const int nIss = (wv < 3) ? 4 : 2;            // per-wave B issues (+1 A issue)
  const int fr = lane & 15, fq = lane >> 4;

  f32x4 acc[14];
  #pragma unroll
  for (int j = 0; j < 14; j++) acc[j] = (f32x4){0.f,0.f,0.f,0.f};

  const int nk = 32;
  // prologue: stage tiles 0 and 1
  #pragma unroll
  for (int p = 0; p < 2; p++) {
    gl_lds16(ga + p*32, lA + p*ABUF);
    for (int i = 0; i < nIss; i++)
      gl_lds16(gb + p*32 + (long)i*16*DIMD, lB + p*BBUF + i*16*32);
  }
  for (int t = 0; t < nk; ++t) {
    const int cur = t % 3;
    if (t + 2 < nk) {
      const int nb = (t + 2) % 3;
      const int k2 = (t + 2) << 5;
      gl_lds16(ga + k2, lA + nb*ABUF);
      for (int i = 0; i < nIss; i++)
        gl_lds16(gb + k2 + (long)i*16*DIMD, lB + nb*BBUF + i*16*32);
    }
    const int ahead = (nk - 1 - t > 2) ? 2 : (nk - 1 - t);
    if (wv < 3) {      // 5 loads/stage
      if (ahead == 2)      asm volatile("s_waitcnt vmcnt(10)" ::: "memory");
      else if (ahead == 1) asm volatile("s_waitcnt vmcnt(5)"  ::: "memory");
      else                 asm volatile("s_waitcnt vmcnt(0)"  ::: "memory");
    } else {           // 3 loads/stage
      if (ahead == 2)      asm volatile("s_waitcnt vmcnt(6)"  ::: "memory");
      else if (ahead == 1) asm volatile("s_waitcnt vmcnt(3)"  ::: "memory");
      else                 asm volatile("s_waitcnt vmcnt(0)"  ::: "memory");
    }
    __builtin_amdgcn_s_barrier();
    const bf16* Ab = &As[cur][0];
    const bf16* Bb = &Bs[cur][0];
    bf16x8 af = *(const bf16x8*)(Ab + (wv*16 + fr)*32 + fq*8);
    #pragma unroll
    for (int j = 0; j < 14; j++) {
      bf16x8 bfr = *(const bf16x8*)(Bb + (j*16 + fr)*32 + fq*8);
      acc[j] = __builtin_amdgcn_mfma_f32_16x16x32_bf16(af, bfr, acc[j], 0, 0, 0);
    }
    asm volatile("s_waitcnt lgkmcnt(0)" ::: "memory");
    __builtin_amdgcn_s_barrier();
  }

  // per-row softmax: row = y0 + wv*16 + fq*4 + r; cols j*16 + fr
  const bf16 bzero = __float2bfloat16(0.f);
  #pragma unroll
  for (int r = 0; r < 4; r++) {
    float mx = -INFINITY;
    #pragma unroll
    for (int j = 0; j < 14; j++) {
      int col = j*16 + fr;
      if (col < NTOK) mx = fmaxf(mx, acc[j][r]);
    }
    #pragma unroll
    for (int off = 1; off < 16; off <<= 1) mx = fmaxf(mx, __shfl_xor(mx, off));
    float e[14];
    float s = 0.f;
    #pragma unroll
    for (int j = 0; j < 14; j++) {
      int col = j*16 + fr;
      e[j] = (col < NTOK) ? __expf((acc[j][r] - mx) * scale) : 0.f;
      s += e[j];
    }
    #pragma unroll
    for (int off = 1; off < 16; off <<= 1) s += __shfl_xor(s, off);
    float inv = 1.f / s;
    int grow = y0 + wv*16 + fq*4 + r;
    bf16* dst = Apad + ((long)z*APAD_R + grow)*APAD_C;
    #pragma unroll
    for (int j = 0; j < 14; j++) {
      int col = j*16 + fr;
      float outv = (grow < NTOK) ? e[j]*inv : 0.f;   // col>=196 -> e=0 -> writes 0
      dst[col] = __float2bfloat16(outv);
    }
    dst[224 + fr] = bzero;   // zero-fill padded K cols [224,256)
    dst[240 + fr] = bzero;
  }
}

// ====== V-GEMM direct-Gt: Gt[z][h*128+d][t] = sum_e WVt[d][e]*xnb[z*196+t][h*128+e] ======
// K=128: stage the ENTIRE K up front (4 chunks), one drain, then barrier-free MFMA loop.
// Token cols [196,256) zero-filled (grid.x=2 covers 256 cols with APAD_C=256).
__global__ __launch_bounds__(256) void gemm_v(
    const bf16* __restrict__ WVt, const bf16* __restrict__ xnb, bf16* __restrict__ Gt) {
  __shared__ __align__(16) bf16 As[4][128*32];   // 32 KB
  __shared__ __align__(16) bf16 Bs[4][128*32];   // 32 KB
  const int CH = 128*32;
  int bx, by, bz;
  xcd_swizzle(bx, by, bz);
  const int z = bz, h = by, n0 = bx*128;
  const int tid = threadIdx.x, lane = tid & 63, wv = tid >> 6;
  const int lrow = lane >> 2, lchunk = lane & 3;
  const bf16* ga = WVt + (long)(wv*32 + lrow)*HD + lchunk*8;
  const bf16* gb = xnb + (long)(z*NTOK + n0 + wv*32 + lrow)*DIMD + h*HD + lchunk*8;
  bf16* lA = &As[0][(wv*32)*32];
  bf16* lB = &Bs[0][(wv*32)*32];
  const int mBase = (wv & 1)*64, nBase = (wv >> 1)*64;
  const int fr = lane & 15, fq = lane >> 4;

  f32x4 acc[4][4];
  #pragma unroll
  for (int i = 0; i < 4; i++)
    #pragma unroll
    for (int j = 0; j < 4; j++) acc[i][j] = (f32x4){0.f,0.f,0.f,0.f};

  #pragma unroll
  for (int c = 0; c < 4; c++) {
    gl_lds16(ga + c*32,           lA + c*CH);
    gl_lds16(ga + c*32 + 16*HD,   lA + c*CH + 16*32);
    gl_lds16(gb + c*32,           lB + c*CH);
    gl_lds16(gb + c*32 + 16*DIMD, lB + c*CH + 16*32);
  }
  asm volatile("s_waitcnt vmcnt(0)" ::: "memory");
  __syncthreads();

  #pragma unroll
  for (int c = 0; c < 4; c++) {
    const bf16* Ab = &As[c][0];
    const bf16* Bb = &Bs[c][0];
    bf16x8 af[4], bfr[4];
    #pragma unroll
    for (int mi = 0; mi < 4; mi++)
      af[mi] = *(const bf16x8*)(Ab + (mBase + mi*16 + fr)*32 + fq*8);
    #pragma unroll
    for (int ni = 0; ni < 4; ni++)
      bfr[ni] = *(const bf16x8*)(Bb + (nBase + ni*16 + fr)*32 + fq*8);
    #pragma unroll
    for (int mi = 0; mi < 4; mi++)
      #pragma unroll
      for (int ni = 0; ni < 4; ni++)
        acc[mi][ni] = __builtin_amdgcn_mfma_f32_16x16x32_bf16(af[mi], bfr[ni], acc[mi][ni], 0, 0, 0);
  }

  #pragma unroll
  for (int mi = 0; mi < 4; mi++)
    #pragma unroll
    for (int ni = 0; ni < 4; ni++)
      #pragma unroll
      for (int r = 0; r < 4; r++) {
        int gm = mBase + mi*16 + fq*4 + r;          // output dim within head (0..127)
        int gn = n0 + nBase + ni*16 + fr;           // token
        if (gn < NTOK)
          Gt[((long)z*DIMD + h*HD + gm)*APAD_C + gn] = __float2bfloat16(acc[mi][ni][r]);
        else if (gn < APAD_C)
          Gt[((long)z*DIMD + h*HD + gm)*APAD_C + gn] = __float2bfloat16(0.f);
      }
}

// ================= classifier split-K (K=128: full up-front staging) =================
__global__ __launch_bounds__(256) void gemm_cls(
    const bf16* __restrict__ A, const bf16* __restrict__ Bt,
    float* __restrict__ Cp) {
  __shared__ __align__(16) bf16 As[4][64*32];    // 16 KB
  __shared__ __align__(16) bf16 Bs[4][128*32];   // 32 KB
  const int ACH = 64*32, BCH = 128*32;
  const int n0 = blockIdx.x*128, kz = blockIdx.y;
  const int tid = threadIdx.x, lane = tid & 63, wv = tid >> 6;
  const bf16* ga = A + (tid>>2)*DIMD + kz*128 + (tid&3)*8;
  const bf16* gb = Bt + (long)(n0 + wv*32 + (lane>>2))*DIMD + kz*128 + (lane&3)*8;
  bf16* lA = &As[0][wv*512];
  bf16* lB = &Bs[0][(wv*32)*32];
  const int fr = lane & 15, fq = lane >> 4;
  f32x4 acc[4][2];
  #pragma unroll
  for (int i = 0; i < 4; i++)
    #pragma unroll
    for (int j = 0; j < 2; j++) acc[i][j] = (f32x4){0.f,0.f,0.f,0.f};
  #pragma unroll
  for (int it = 0; it < 4; it++) {
    gl_lds16(ga + it*32, lA + it*ACH);
    gl_lds16(gb + it*32,            lB + it*BCH);
    gl_lds16(gb + it*32 + 16*DIMD,  lB + it*BCH + 16*32);
  }
  asm volatile("s_waitcnt vmcnt(0)" ::: "memory");
  __syncthreads();
  #pragma unroll
  for (int it = 0; it < 4; it++) {
    const bf16* Ab = &As[it][0];
    const bf16* Bb = &Bs[it][0];
    bf16x8 af[4], bfr[2];
    #pragma unroll
    for (int mi = 0; mi < 4; mi++)
      af[mi] = *(const bf16x8*)(Ab + (mi*16 + fr)*32 + fq*8);
    #pragma unroll
    for (int ni = 0; ni < 2; ni++)
      bfr[ni] = *(const bf16x8*)(Bb + (wv*32 + ni*16 + fr)*32 + fq*8);
    #pragma unroll
    for (int mi = 0; mi < 4; mi++)
      #pragma unroll
      for (int ni = 0; ni < 2; ni++)
        acc[mi][ni] = __builtin_amdgcn_mfma_f32_16x16x32_bf16(af[mi], bfr[ni], acc[mi][ni], 0, 0, 0);
  }
  #pragma unroll
  for (int mi = 0; mi < 4; mi++)
    #pragma unroll
    for (int ni = 0; ni < 2; ni++)
      #pragma unroll
      for (int r = 0; r < 4; r++) {
        int gm = mi*16 + fq*4 + r;
        int gn = n0 + wv*32 + ni*16 + fr;
        Cp[((long)kz*64 + gm)*DIMD + gn] = acc[mi][ni][r];
      }
}

__global__ __launch_bounds__(256) void cls_reduce(
    const float* __restrict__ Cp, const float* __restrict__ bias,
    float* __restrict__ out) {
  int i = blockIdx.x*256 + threadIdx.x;
  int m = i / 1000, n = i - m*1000;
  float s = bias[n];
  #pragma unroll
  for (int kz = 0; kz < 8; kz++) s += Cp[((long)kz*64 + m)*DIMD + n];
  out[i] = s;
}

// ================= patchify + LN1 (dim 768) -> bf16 =================
__global__ __launch_bounds__(256) void patchify_ln(
    const float* __restrict__ img, const float* __restrict__ g,
    const float* __restrict__ b, bf16* __restrict__ out) {
  int t = blockIdx.x;
  int bi = t / NTOK, n = t % NTOK;
  int ph = n / 14, pw = n % 14;
  __shared__ float vals[PD];
  __shared__ float part[8];
  int tid = threadIdx.x;
  int lane = tid & 63, wv = tid >> 6;
  for (int j = tid; j < PD; j += 256) {
    int p1 = j / 48, rem = j % 48, p2 = rem / 3, c = rem % 3;
    vals[j] = img[(((long)bi*3 + c)*224 + (ph*16 + p1))*224 + (pw*16 + p2)];
  }
  __syncthreads();
  float s = 0.f;
  for (int j = tid; j < PD; j += 256) s += vals[j];
  #pragma unroll
  for (int off = 1; off < 64; off <<= 1) s += __shfl_xor(s, off);
  if (lane == 0) part[wv] = s;
  __syncthreads();
  float mean = (part[0]+part[1]+part[2]+part[3]) / (float)PD;
  float s2 = 0.f;
  for (int j = tid; j < PD; j += 256) { float d = vals[j]-mean; s2 += d*d; }
  #pragma unroll
  for (int off = 1; off < 64; off <<= 1) s2 += __shfl_xor(s2, off);
  if (lane == 0) part[4+wv] = s2;
  __syncthreads();
  float rstd = rsqrtf((part[4]+part[5]+part[6]+part[7])/(float)PD + LN_EPS);
  for (int j = tid; j < PD; j += 256)
    out[(long)t*PD + j] = __float2bfloat16((vals[j]-mean)*rstd*g[j] + b[j]);
}

// ================= LayerNorm rows (dim=1024): optional fp32 out, optional bf16 out =================
__global__ __launch_bounds__(256) void ln_rows2(
    const float* __restrict__ in, const float* __restrict__ g,
    const float* __restrict__ b, const float* __restrict__ pos,
    float* __restrict__ outf, ushort4* __restrict__ outb) {
  long t = blockIdx.x;
  int tid = threadIdx.x;
  int lane = tid & 63, wv = tid >> 6;
  float4 v = ((const float4*)(in + t*DIMD))[tid];
  float s  = v.x+v.y+v.z+v.w;
  float s2 = v.x*v.x+v.y*v.y+v.z*v.z+v.w*v.w;
  #pragma unroll
  for (int off = 1; off < 64; off <<= 1) {
    s  += __shfl_xor(s, off);
    s2 += __shfl_xor(s2, off);
  }
  __shared__ float ps[4], pq[4];
  if (lane == 0) { ps[wv] = s; pq[wv] = s2; }
  __syncthreads();
  s  = ps[0]+ps[1]+ps[2]+ps[3];
  s2 = pq[0]+pq[1]+pq[2]+pq[3];
  float mean = s*(1.f/1024.f);
  float var  = s2*(1.f/1024.f) - mean*mean;
  float rstd = rsqrtf(var + LN_EPS);
  float4 gg = ((const float4*)g)[tid];
  float4 bb = ((const float4*)b)[tid];
  float4 o;
  o.x = (v.x-mean)*rstd*gg.x + bb.x;
  o.y = (v.y-mean)*rstd*gg.y + bb.y;
  o.z = (v.z-mean)*rstd*gg.z + bb.z;
  o.w = (v.w-mean)*rstd*gg.w + bb.w;
  if (pos) {
    float4 pp = ((const float4*)(pos + (long)(t % NTOK)*DIMD))[tid];
    o.x += pp.x; o.y += pp.y; o.z += pp.z; o.w += pp.w;
  }
  if (outf) ((float4*)(outf + t*DIMD))[tid] = o;
  if (outb) {
    ushort4 u;
    u.x = bfbits(o.x); u.y = bfbits(o.y); u.z = bfbits(o.z); u.w = bfbits(o.w);
    outb[t*256 + tid] = u;
  }
}

// ================= cast + transpose weights: fp32 [R][C] -> bf16 [C][R] =================
__global__ void castT(const float* __restrict__ src, bf16* __restrict__ dst, int R, int C) {
  __shared__ float t[32][33];
  int rb = blockIdx.y*32, cb = blockIdx.x*32;
  int tx = threadIdx.x, ty = threadIdx.y;  // (32,8)
  for (int i = ty; i < 32; i += 8)
    if (rb+i < R && cb+tx < C) t[i][tx] = src[(long)(rb+i)*C + cb+tx];
  __syncthreads();
  for (int i = ty; i < 32; i += 8)
    if (cb+i < C && rb+tx < R) dst[(long)(cb+i)*R + rb+tx] = __float2bfloat16(t[tx][i]);
}

// ================= natural cast fp32 -> bf16 (elementwise, float4) =================
__global__ __launch_bounds__(256) void castN(
    const float* __restrict__ src, ushort4* __restrict__ dst) {
  int i = blockIdx.x*256 + threadIdx.x;
  float4 v = ((const float4*)src)[i];
  ushort4 u;
  u.x = bfbits(v.x); u.y = bfbits(v.y); u.z = bfbits(v.z); u.w = bfbits(v.w);
  dst[i] = u;
}

// ================= mean over tokens -> bf16 =================
__global__ __launch_bounds__(256) void mean_tokens(
    const float* __restrict__ x, bf16* __restrict__ outb) {
  int b = blockIdx.x;
  int d = blockIdx.y*256 + threadIdx.x;
  const float* p = x + (long)b*NTOK*DIMD + d;
  float s = 0.f;
  #pragma unroll 4
  for (int n = 0; n < NTOK; n++) s += p[(long)n*DIMD];
  outb[(long)b*DIMD + d] = __float2bfloat16(s * (1.f/196.f));
}

extern "C" void kernel_launch(void* const* d_in, const int* in_sizes, int n_in,
                              void* d_out, int out_size, void* d_ws, size_t ws_size,
                              hipStream_t stream) {
  (void)in_sizes; (void)n_in; (void)out_size; (void)ws_size;
  const float* image = (const float*)d_in[0];
  const float* ln1_g = (const float*)d_in[1];
  const float* ln1_b = (const float*)d_in[2];
  const float* W_emb = (const float*)d_in[3];
  const float* b_emb = (const float*)d_in[4];
  const float* ln2_g = (const float*)d_in[5];
  const float* ln2_b = (const float*)d_in[6];
  const float* pos   = (const float*)d_in[7];
  const float* norm_g= (const float*)d_in[8];
  const float* norm_b= (const float*)d_in[9];
  const float* WV    = (const float*)d_in[10];
  const float* WK    = (const float*)d_in[11];
  const float* WQ    = (const float*)d_in[12];
  const float* lastW = (const float*)d_in[13];
  const float* lastb = (const float*)d_in[14];
  float* out = (float*)d_out;

  char* W = (char*)d_ws;
  float* x     = (float*)(W);                      // 51,380,224
  bf16*  xnb   = (bf16*) (W + 51380224);           // 25,690,112
  bf16*  xm    = (bf16*) (W + 77070336);           // 25.7MB in 51.6MB slab (alias Xp; overread zone)
  bf16*  Xp    = xm;
  // slabB: embed-phase xn (fp32 51.4 MB) OR layer-phase Gt+Apad
  float* xn    = (float*)(W + 128712704);
  bf16*  Gt    = (bf16*) (W + 128712704);          // 33,554,432 (64 x 1024 x 256 bf16)
  bf16*  Apad  = (bf16*) (W + 162267136);          //  8,388,608 (64 x 256 x 256 bf16)
  bf16*  WembT = (bf16*) (W + 180092928);          //  1,572,864
  bf16*  WQb   = (bf16*) (W + 181665792);          //  2,097,152 (natural layout)
  bf16*  WKb   = (bf16*) (W + 183762944);          //  2,097,152 (natural layout)
  bf16*  WVt   = (bf16*) (W + 185860096);          //     32,768
  bf16*  lastWT= (bf16*) (W + 185892864);          //  2,097,152
  bf16*  meanxb= (bf16*) (W + 187990016);          //    131,072
  float* clsPart=(float*)(W + 188121088);          //  2,097,152
  bf16*  Mt    = (bf16*) (W + 190218240);          //  2,097,152 (M^T = WK @ WQ^T)

  dim3 blk(256);
  dim3 blk512(512);
  const float scale = 0.08838834764831845f;  // 128^-0.5
  const long ZR = 0;

  // weight casts
  castT<<<dim3(32, 24), dim3(32, 8), 0, stream>>>(W_emb, WembT, PD, DIMD);
  castN<<<1024, blk, 0, stream>>>(WQ, (ushort4*)WQb);
  castN<<<1024, blk, 0, stream>>>(WK, (ushort4*)WKb);
  castT<<<dim3(4, 4),  dim3(32, 8), 0, stream>>>(WV, WVt, HD, HD);
  castT<<<dim3(32, 32), dim3(32, 8), 0, stream>>>(lastW, lastWT, DIMD, 1000);
  // Mt[j][i] = sum_k WK[j][k]*WQ[i][k]  (= (WQ @ WK^T)^T); M=1024 -> 4 x 256-row tiles
  gemm_mfma<<<dim3(8, 4, 1), blk512, 0, stream>>>(
      WKb, DIMD, ZR, WQb, DIMD, ZR, DIMD, 1,
      nullptr, Mt, DIMD, ZR, nullptr, nullptr, ZR, 1.f, DIMD, DIMD);

  // patch embed  (M=12544 = 49 x 256 exactly)
  patchify_ln<<<TOKENS, blk, 0, stream>>>(image, ln1_g, ln1_b, Xp);
  gemm_mfma<<<dim3(8, 49, 1), blk512, 0, stream>>>(
      Xp, PD, ZR, WembT, PD, ZR, PD, 0,
      xn, nullptr, DIMD, ZR, b_emb, nullptr, ZR, 1.f, TOKENS, DIMD);
  ln_rows2<<<TOKENS, blk, 0, stream>>>(xn, ln2_g, ln2_b, pos, x, nullptr);

  for (int l = 0; l < DEPTH; l++) {
    // xnb = bf16(LN(x))
    ln_rows2<<<TOKENS, blk, 0, stream>>>(x, norm_g, norm_b, nullptr, nullptr, (ushort4*)xnb);
    // xm = xnb @ M
    gemm_mfma<<<dim3(8, 49, 1), blk512, 0, stream>>>(
        xnb, DIMD, ZR, Mt, DIMD, ZR, DIMD, 1,
        nullptr, xm, DIMD, ZR, nullptr, nullptr, ZR, 1.f, TOKENS, DIMD);
    // Apad = softmax(xm @ xnb^T * scale), fused, pads (rows>=196, cols>=196) zeroed
    gemm_qs<<<dim3(1, 4, BATCH), blk, 0, stream>>>(xm, xnb, Apad, scale);
    // Gt[b][dim][tok] = WV^T @ xn^T  (direct transposed layout, pad cols zeroed)
    gemm_v<<<dim3(2, HEADS, BATCH), blk, 0, stream>>>(WVt, xnb, Gt);
    // x = Apad @ G + xnb (bf16 residual): padded-K AV product via the 256x128 GEMM.
    // K=256 (cols [196,256) zero on both operands -> exact +0 terms).
    gemm_mfma<<<dim3(8, 1, BATCH), blk512, 0, stream>>>(
        Apad, APAD_C, (long)APAD_R*APAD_C, Gt, APAD_C, (long)DIMD*APAD_C, APAD_C, 0,
        x, nullptr, DIMD, (long)NTOK*DIMD, nullptr, xnb, (long)NTOK*DIMD, 1.f, NTOK, DIMD);
  }

  // classifier
  mean_tokens<<<dim3(BATCH, 4), blk, 0, stream>>>(x, meanxb);
  gemm_cls<<<dim3(8, 8), blk, 0, stream>>>(meanxb, lastWT, clsPart);
  cls_reduce<<<250, blk, 0, stream>>>(clsPart, lastb, out);
}

// Round 13
// 1004.642 us; speedup vs baseline: 1.2991x; 1.0472x over previous
//
#include <hip/hip_runtime.h>
#include <hip/hip_bf16.h>
#include <math.h>

#define NTOK   196
#define BATCH  64
#define TOKENS (BATCH*NTOK)   // 12544
#define DIMD   1024
#define PD     768
#define HEADS  8
#define HD     128
#define DEPTH  6
#define LN_EPS 1e-5f
#define APAD_R 256            // padded A rows per batch (for 256-row tiles)
#define APAD_C 256            // padded K dim for A@G (4*64; cols 196..256 zeroed)

typedef __hip_bfloat16 bf16;
typedef __attribute__((ext_vector_type(8))) short bf16x8;
typedef __attribute__((ext_vector_type(4))) float f32x4;

typedef const __attribute__((address_space(1))) void* gptr_t;
typedef __attribute__((address_space(3))) void* lptr_t;

__device__ __forceinline__ void gl_lds16(const bf16* g, bf16* l) {
  __builtin_amdgcn_global_load_lds((gptr_t)(const void*)g, (lptr_t)(void*)l, 16, 0, 0);
}
__device__ __forceinline__ unsigned short bfbits(float f) {
  bf16 h = __float2bfloat16(f);
  return *(unsigned short*)&h;
}

// XCD-aware bijective swizzle (requires nwg % 8 == 0, true for all call sites):
// physical block f runs work item (f%8)*(nwg/8) + f/8, so each XCD gets a
// CONTIGUOUS range of work ids -> operand-panel-sharing blocks co-locate on one L2.
__device__ __forceinline__ void xcd_swizzle(int& bx, int& by, int& bz) {
  const int gx = gridDim.x, gy = gridDim.y;
  const int nwg = gx*gy*gridDim.z;
  const int flat = blockIdx.x + gx*(blockIdx.y + gy*blockIdx.z);
  const int swz = (flat & 7)*(nwg >> 3) + (flat >> 3);
  bx = swz % gx;
  const int rest = swz / gx;
  by = rest % gy;
  bz = rest / gy;
}

// ================= generic MFMA GEMM: C[m][n] = sum_k A[m][k] * Bt[n][k] =================
// 256x128 tile, 512 threads (8 waves, each a 64x64 quadrant: 4 rows x 2 cols of waves),
// BK=64 (two [.][32] chunks per barrier pair). Measured r11: staging service ~6 TB/s
// at this shape (vs 2.5 TB/s for the 128^2 tile). Single LDS buffer 48 KB -> 3 blocks/CU.
// K-accumulation order per fragment unchanged -> bit-identical output.
// mode 0: Cf = acc*alpha (+bias)(+bf16 res); mode 1: Cb = bf16(acc)
__global__ __launch_bounds__(512) void gemm_mfma(
    const bf16* __restrict__ A, int lda, long aStride,
    const bf16* __restrict__ Bt, int ldb, long bStride,
    int K, int mode,
    float* __restrict__ Cf, bf16* __restrict__ Cb, int ldc, long cStride,
    const float* __restrict__ bias, const bf16* __restrict__ resb, long resStride,
    float alpha, int Mb, int Nb) {
  __shared__ __align__(16) bf16 As[2*256*32];   // 32 KB (2 chunks x 256 rows x 32 cols)
  __shared__ __align__(16) bf16 Bs[2*128*32];   // 16 KB
  const int CHA = 256*32, CHB = 128*32;
  int bx, by, bz;
  xcd_swizzle(bx, by, bz);
  const int z = bz;
  A  += (long)z*aStride;
  Bt += (long)z*bStride;
  const int m0 = by*256, n0 = bx*128;
  const int tid = threadIdx.x, lane = tid & 63, wv = tid >> 6;   // wv 0..7
  const int lrow = lane >> 2, lchunk = lane & 3;
  // A staging: wave wv owns rows [wv*32, wv*32+32) (2 instrs of 16 rows per chunk)
  const bf16* ga = A + (long)(m0 + wv*32 + lrow)*lda + lchunk*8;
  // B staging: wave wv owns rows [wv*16, wv*16+16) (1 instr per chunk)
  const bf16* gb = Bt + (long)(n0 + wv*16 + lrow)*ldb + lchunk*8;
  bf16* lA = As + (wv*32)*32;
  bf16* lB = Bs + (wv*16)*32;
  // wave quadrant: 4 rows x 2 cols of 64x64
  const int mBase = (wv >> 1)*64, nBase = (wv & 1)*64;
  const int fr = lane & 15, fq = lane >> 4;

  f32x4 acc[4][4];
  #pragma unroll
  for (int i = 0; i < 4; i++)
    #pragma unroll
    for (int j = 0; j < 4; j++) acc[i][j] = (f32x4){0.f,0.f,0.f,0.f};

  const int nk = K >> 6;   // BK=64; all call sites have K % 64 == 0
  for (int t = 0; t < nk; ++t) {
    const int k0 = t << 6;
    #pragma unroll
    for (int c = 0; c < 2; c++) {
      gl_lds16(ga + k0 + c*32,          lA + c*CHA);
      gl_lds16(ga + k0 + c*32 + 16*lda, lA + c*CHA + 16*32);
      gl_lds16(gb + k0 + c*32,          lB + c*CHB);
    }
    asm volatile("s_waitcnt vmcnt(0)" ::: "memory");
    __syncthreads();
    #pragma unroll
    for (int c = 0; c < 2; c++) {
      const bf16* Ab = As + c*CHA;
      const bf16* Bb = Bs + c*CHB;
      bf16x8 af[4], bfr[4];
      #pragma unroll
      for (int mi = 0; mi < 4; mi++)
        af[mi] = *(const bf16x8*)(Ab + (mBase + mi*16 + fr)*32 + fq*8);
      #pragma unroll
      for (int ni = 0; ni < 4; ni++)
        bfr[ni] = *(const bf16x8*)(Bb + (nBase + ni*16 + fr)*32 + fq*8);
      #pragma unroll
      for (int mi = 0; mi < 4; mi++)
        #pragma unroll
        for (int ni = 0; ni < 4; ni++)
          acc[mi][ni] = __builtin_amdgcn_mfma_f32_16x16x32_bf16(af[mi], bfr[ni], acc[mi][ni], 0, 0, 0);
    }
    __syncthreads();
  }

  #pragma unroll
  for (int mi = 0; mi < 4; mi++)
    #pragma unroll
    for (int ni = 0; ni < 4; ni++)
      #pragma unroll
      for (int r = 0; r < 4; r++) {
        int gm = m0 + mBase + mi*16 + fq*4 + r;
        int gn = n0 + nBase + ni*16 + fr;
        if (gm >= Mb || gn >= Nb) continue;
        float v = acc[mi][ni][r] * alpha;
        if (mode == 0) {
          if (bias) v += bias[gn];
          if (resb) v += __bfloat162float(resb[(long)z*resStride + (long)gm*ldc + gn]);
          Cf[(long)z*cStride + (long)gm*ldc + gn] = v;
        } else {
          Cb[(long)z*cStride + (long)gm*ldc + gn] = __float2bfloat16(v);
        }
      }
}

// ================= AV GEMM, 256x256 tile: x[z] = Apad[z] @ Gt[z]^T + xnb[z] =================
// 1024 threads, 16 waves (4M x 4N), each wave the SAME proven 64x64 quadrant / 16xf32x4
// accumulator as gemm_mfma. BK=64, K=256 (padded; cols [196,256) zero on both operands).
// vs the 256x128 AV call: Apad re-staged 4x instead of 8x -> staged volume 98 -> 66 MB,
// per-CU traffic 768 -> 640 KB. LDS 64 KB. grid (4,1,64) = 256 blocks (nwg%8==0).
__global__ __launch_bounds__(1024) void gemm_av256(
    const bf16* __restrict__ Apad, const bf16* __restrict__ Gt,
    const bf16* __restrict__ resb, float* __restrict__ Cf) {
  __shared__ __align__(16) bf16 As[2*256*32];   // 32 KB
  __shared__ __align__(16) bf16 Bs[2*256*32];   // 32 KB
  const int CH = 256*32;
  int bx, by, bz;
  xcd_swizzle(bx, by, bz);
  (void)by;
  const int z = bz, n0 = bx*256;
  const int tid = threadIdx.x, lane = tid & 63, wv = tid >> 6;   // wv 0..15
  const int lrow = lane >> 2, lchunk = lane & 3;
  // staging: wave wv owns rows [wv*16, wv*16+16) of BOTH A (Apad) and B (Gt) per chunk
  const bf16* ga = Apad + ((long)z*APAD_R + wv*16 + lrow)*APAD_C + lchunk*8;
  const bf16* gb = Gt   + ((long)z*DIMD  + n0 + wv*16 + lrow)*APAD_C + lchunk*8;
  bf16* lA = As + (wv*16)*32;
  bf16* lB = Bs + (wv*16)*32;
  // wave quadrant: 4 rows x 4 cols of 64x64
  const int mBase = (wv >> 2)*64, nBase = (wv & 3)*64;
  const int fr = lane & 15, fq = lane >> 4;

  f32x4 acc[4][4];
  #pragma unroll
  for (int i = 0; i < 4; i++)
    #pragma unroll
    for (int j = 0; j < 4; j++) acc[i][j] = (f32x4){0.f,0.f,0.f,0.f};

  const int nk = APAD_C >> 6;   // 4
  for (int t = 0; t < nk; ++t) {
    const int k0 = t << 6;
    #pragma unroll
    for (int c = 0; c < 2; c++) {
      gl_lds16(ga + k0 + c*32, lA + c*CH);
      gl_lds16(gb + k0 + c*32, lB + c*CH);
    }
    asm volatile("s_waitcnt vmcnt(0)" ::: "memory");
    __syncthreads();
    #pragma unroll
    for (int c = 0; c < 2; c++) {
      const bf16* Ab = As + c*CH;
      const bf16* Bb = Bs + c*CH;
      bf16x8 af[4], bfr[4];
      #pragma unroll
      for (int mi = 0; mi < 4; mi++)
        af[mi] = *(const bf16x8*)(Ab + (mBase + mi*16 + fr)*32 + fq*8);
      #pragma unroll
      for (int ni = 0; ni < 4; ni++)
        bfr[ni] = *(const bf16x8*)(Bb + (nBase + ni*16 + fr)*32 + fq*8);
      #pragma unroll
      for (int mi = 0; mi < 4; mi++)
        #pragma unroll
        for (int ni = 0; ni < 4; ni++)
          acc[mi][ni] = __builtin_amdgcn_mfma_f32_16x16x32_bf16(af[mi], bfr[ni], acc[mi][ni], 0, 0, 0);
    }
    __syncthreads();
  }

  #pragma unroll
  for (int mi = 0; mi < 4; mi++)
    #pragma unroll
    for (int ni = 0; ni < 4; ni++)
      #pragma unroll
      for (int r = 0; r < 4; r++) {
        int gm = mBase + mi*16 + fq*4 + r;
        int gn = n0 + nBase + ni*16 + fr;
        if (gm >= NTOK) continue;
        float v = acc[mi][ni][r]
                + __bfloat162float(resb[(long)z*NTOK*DIMD + (long)gm*DIMD + gn]);
        Cf[(long)z*NTOK*DIMD + (long)gm*DIMD + gn] = v;
      }
}

// ====== fused QKT+softmax: per batch z, 64-row tile x full 224-col width ======
// logits = xm[z] @ xnb[z]^T (fp32 acc), row-softmax with max-sub, writes bf16 Apad
// (stride APAD_C=256; cols [224,256) zero-filled so the padded-K AV GEMM sees no
// garbage -- Gt cols [196,256) are also zero, so padded products are exactly 0).
// Depth-3 ring pipeline (1 block/CU -> prefetch is the only latency hiding).
__global__ __launch_bounds__(256) void gemm_qs(
    const bf16* __restrict__ xmp, const bf16* __restrict__ xnbp,
    bf16* __restrict__ Apad, float scale) {
  __shared__ __align__(16) bf16 As[3][64*32];
  __shared__ __align__(16) bf16 Bs[3][224*32];
  const int ABUF = 64*32, BBUF = 224*32;
  int bx, by, bz;
  xcd_swizzle(bx, by, bz);
  const int z = bz;
  const int y0 = by*64;                         // 0,64,128,192
  const bf16* A  = xmp  + (long)z*NTOK*DIMD;
  const bf16* Bt = xnbp + (long)z*NTOK*DIMD;
  const int tid = threadIdx.x, lane = tid & 63, wv = tid >> 6;
  const int lrow = lane >> 2, lchunk = lane & 3;
  const bf16* ga = A + (long)(y0 + wv*16 + lrow)*DIMD + lchunk*8;
  bf16* lA = &As[0][(wv*16)*32];
  const bf16* gb = Bt + (long)(wv*64 + lrow)*DIMD + lchunk*8;
  bf16* lB = &Bs[0][(wv*64)*32];
  const int nIss = (wv < 3) ? 4 : 2;            // per-wave B issues (+1 A issue)
  const int fr = lane & 15, fq = lane >> 4;

  f32x4 acc[14];
  #pragma unroll
  for (int j = 0; j < 14; j++) acc[j] = (f32x4){0.f,0.f,0.f,0.f};

  const int nk = 32;
  // prologue: stage tiles 0 and 1
  #pragma unroll
  for (int p = 0; p < 2; p++) {
    gl_lds16(ga + p*32, lA + p*ABUF);
    for (int i = 0; i < nIss; i++)
      gl_lds16(gb + p*32 + (long)i*16*DIMD, lB + p*BBUF + i*16*32);
  }
  for (int t = 0; t < nk; ++t) {
    const int cur = t % 3;
    if (t + 2 < nk) {
      const int nb = (t + 2) % 3;
      const int k2 = (t + 2) << 5;
      gl_lds16(ga + k2, lA + nb*ABUF);
      for (int i = 0; i < nIss; i++)
        gl_lds16(gb + k2 + (long)i*16*DIMD, lB + nb*BBUF + i*16*32);
    }
    const int ahead = (nk - 1 - t > 2) ? 2 : (nk - 1 - t);
    if (wv < 3) {      // 5 loads/stage
      if (ahead == 2)      asm volatile("s_waitcnt vmcnt(10)" ::: "memory");
      else if (ahead == 1) asm volatile("s_waitcnt vmcnt(5)"  ::: "memory");
      else                 asm volatile("s_waitcnt vmcnt(0)"  ::: "memory");
    } else {           // 3 loads/stage
      if (ahead == 2)      asm volatile("s_waitcnt vmcnt(6)"  ::: "memory");
      else if (ahead == 1) asm volatile("s_waitcnt vmcnt(3)"  ::: "memory");
      else                 asm volatile("s_waitcnt vmcnt(0)"  ::: "memory");
    }
    __builtin_amdgcn_s_barrier();
    const bf16* Ab = &As[cur][0];
    const bf16* Bb = &Bs[cur][0];
    bf16x8 af = *(const bf16x8*)(Ab + (wv*16 + fr)*32 + fq*8);
    #pragma unroll
    for (int j = 0; j < 14; j++) {
      bf16x8 bfr = *(const bf16x8*)(Bb + (j*16 + fr)*32 + fq*8);
      acc[j] = __builtin_amdgcn_mfma_f32_16x16x32_bf16(af, bfr, acc[j], 0, 0, 0);
    }
    asm volatile("s_waitcnt lgkmcnt(0)" ::: "memory");
    __builtin_amdgcn_s_barrier();
  }

  // per-row softmax: row = y0 + wv*16 + fq*4 + r; cols j*16 + fr
  const bf16 bzero = __float2bfloat16(0.f);
  #pragma unroll
  for (int r = 0; r < 4; r++) {
    float mx = -INFINITY;
    #pragma unroll
    for (int j = 0; j < 14; j++) {
      int col = j*16 + fr;
      if (col < NTOK) mx = fmaxf(mx, acc[j][r]);
    }
    #pragma unroll
    for (int off = 1; off < 16; off <<= 1) mx = fmaxf(mx, __shfl_xor(mx, off));
    float e[14];
    float s = 0.f;
    #pragma unroll
    for (int j = 0; j < 14; j++) {
      int col = j*16 + fr;
      e[j] = (col < NTOK) ? __expf((acc[j][r] - mx) * scale) : 0.f;
      s += e[j];
    }
    #pragma unroll
    for (int off = 1; off < 16; off <<= 1) s += __shfl_xor(s, off);
    float inv = 1.f / s;
    int grow = y0 + wv*16 + fq*4 + r;
    bf16* dst = Apad + ((long)z*APAD_R + grow)*APAD_C;
    #pragma unroll
    for (int j = 0; j < 14; j++) {
      int col = j*16 + fr;
      float outv = (grow < NTOK) ? e[j]*inv : 0.f;   // col>=196 -> e=0 -> writes 0
      dst[col] = __float2bfloat16(outv);
    }
    dst[224 + fr] = bzero;   // zero-fill padded K cols [224,256)
    dst[240 + fr] = bzero;
  }
}

// ====== V-GEMM direct-Gt: Gt[z][h*128+d][t] = sum_e WVt[d][e]*xnb[z*196+t][h*128+e] ======
// K=128: stage the ENTIRE K up front (4 chunks), one drain, then barrier-free MFMA loop.
// Token cols [196,256) zero-filled (grid.x=2 covers 256 cols with APAD_C=256).
__global__ __launch_bounds__(256) void gemm_v(
    const bf16* __restrict__ WVt, const bf16* __restrict__ xnb, bf16* __restrict__ Gt) {
  __shared__ __align__(16) bf16 As[4][128*32];   // 32 KB
  __shared__ __align__(16) bf16 Bs[4][128*32];   // 32 KB
  const int CH = 128*32;
  int bx, by, bz;
  xcd_swizzle(bx, by, bz);
  const int z = bz, h = by, n0 = bx*128;
  const int tid = threadIdx.x, lane = tid & 63, wv = tid >> 6;
  const int lrow = lane >> 2, lchunk = lane & 3;
  const bf16* ga = WVt + (long)(wv*32 + lrow)*HD + lchunk*8;
  const bf16* gb = xnb + (long)(z*NTOK + n0 + wv*32 + lrow)*DIMD + h*HD + lchunk*8;
  bf16* lA = &As[0][(wv*32)*32];
  bf16* lB = &Bs[0][(wv*32)*32];
  const int mBase = (wv & 1)*64, nBase = (wv >> 1)*64;
  const int fr = lane & 15, fq = lane >> 4;

  f32x4 acc[4][4];
  #pragma unroll
  for (int i = 0; i < 4; i++)
    #pragma unroll
    for (int j = 0; j < 4; j++) acc[i][j] = (f32x4){0.f,0.f,0.f,0.f};

  #pragma unroll
  for (int c = 0; c < 4; c++) {
    gl_lds16(ga + c*32,           lA + c*CH);
    gl_lds16(ga + c*32 + 16*HD,   lA + c*CH + 16*32);
    gl_lds16(gb + c*32,           lB + c*CH);
    gl_lds16(gb + c*32 + 16*DIMD, lB + c*CH + 16*32);
  }
  asm volatile("s_waitcnt vmcnt(0)" ::: "memory");
  __syncthreads();

  #pragma unroll
  for (int c = 0; c < 4; c++) {
    const bf16* Ab = &As[c][0];
    const bf16* Bb = &Bs[c][0];
    bf16x8 af[4], bfr[4];
    #pragma unroll
    for (int mi = 0; mi < 4; mi++)
      af[mi] = *(const bf16x8*)(Ab + (mBase + mi*16 + fr)*32 + fq*8);
    #pragma unroll
    for (int ni = 0; ni < 4; ni++)
      bfr[ni] = *(const bf16x8*)(Bb + (nBase + ni*16 + fr)*32 + fq*8);
    #pragma unroll
    for (int mi = 0; mi < 4; mi++)
      #pragma unroll
      for (int ni = 0; ni < 4; ni++)
        acc[mi][ni] = __builtin_amdgcn_mfma_f32_16x16x32_bf16(af[mi], bfr[ni], acc[mi][ni], 0, 0, 0);
  }

  #pragma unroll
  for (int mi = 0; mi < 4; mi++)
    #pragma unroll
    for (int ni = 0; ni < 4; ni++)
      #pragma unroll
      for (int r = 0; r < 4; r++) {
        int gm = mBase + mi*16 + fq*4 + r;          // output dim within head (0..127)
        int gn = n0 + nBase + ni*16 + fr;           // token
        if (gn < NTOK)
          Gt[((long)z*DIMD + h*HD + gm)*APAD_C + gn] = __float2bfloat16(acc[mi][ni][r]);
        else if (gn < APAD_C)
          Gt[((long)z*DIMD + h*HD + gm)*APAD_C + gn] = __float2bfloat16(0.f);
      }
}

// ================= classifier split-K (K=128: full up-front staging) =================
__global__ __launch_bounds__(256) void gemm_cls(
    const bf16* __restrict__ A, const bf16* __restrict__ Bt,
    float* __restrict__ Cp) {
  __shared__ __align__(16) bf16 As[4][64*32];    // 16 KB
  __shared__ __align__(16) bf16 Bs[4][128*32];   // 32 KB
  const int ACH = 64*32, BCH = 128*32;
  const int n0 = blockIdx.x*128, kz = blockIdx.y;
  const int tid = threadIdx.x, lane = tid & 63, wv = tid >> 6;
  const bf16* ga = A + (tid>>2)*DIMD + kz*128 + (tid&3)*8;
  const bf16* gb = Bt + (long)(n0 + wv*32 + (lane>>2))*DIMD + kz*128 + (lane&3)*8;
  bf16* lA = &As[0][wv*512];
  bf16* lB = &Bs[0][(wv*32)*32];
  const int fr = lane & 15, fq = lane >> 4;
  f32x4 acc[4][2];
  #pragma unroll
  for (int i = 0; i < 4; i++)
    #pragma unroll
    for (int j = 0; j < 2; j++) acc[i][j] = (f32x4){0.f,0.f,0.f,0.f};
  #pragma unroll
  for (int it = 0; it < 4; it++) {
    gl_lds16(ga + it*32, lA + it*ACH);
    gl_lds16(gb + it*32,            lB + it*BCH);
    gl_lds16(gb + it*32 + 16*DIMD,  lB + it*BCH + 16*32);
  }
  asm volatile("s_waitcnt vmcnt(0)" ::: "memory");
  __syncthreads();
  #pragma unroll
  for (int it = 0; it < 4; it++) {
    const bf16* Ab = &As[it][0];
    const bf16* Bb = &Bs[it][0];
    bf16x8 af[4], bfr[2];
    #pragma unroll
    for (int mi = 0; mi < 4; mi++)
      af[mi] = *(const bf16x8*)(Ab + (mi*16 + fr)*32 + fq*8);
    #pragma unroll
    for (int ni = 0; ni < 2; ni++)
      bfr[ni] = *(const bf16x8*)(Bb + (wv*32 + ni*16 + fr)*32 + fq*8);
    #pragma unroll
    for (int mi = 0; mi < 4; mi++)
      #pragma unroll
      for (int ni = 0; ni < 2; ni++)
        acc[mi][ni] = __builtin_amdgcn_mfma_f32_16x16x32_bf16(af[mi], bfr[ni], acc[mi][ni], 0, 0, 0);
  }
  #pragma unroll
  for (int mi = 0; mi < 4; mi++)
    #pragma unroll
    for (int ni = 0; ni < 2; ni++)
      #pragma unroll
      for (int r = 0; r < 4; r++) {
        int gm = mi*16 + fq*4 + r;
        int gn = n0 + wv*32 + ni*16 + fr;
        Cp[((long)kz*64 + gm)*DIMD + gn] = acc[mi][ni][r];
      }
}

__global__ __launch_bounds__(256) void cls_reduce(
    const float* __restrict__ Cp, const float* __restrict__ bias,
    float* __restrict__ out) {
  int i = blockIdx.x*256 + threadIdx.x;
  int m = i / 1000, n = i - m*1000;
  float s = bias[n];
  #pragma unroll
  for (int kz = 0; kz < 8; kz++) s += Cp[((long)kz*64 + m)*DIMD + n];
  out[i] = s;
}

// ================= patchify + LN1 (dim 768) -> bf16 =================
__global__ __launch_bounds__(256) void patchify_ln(
    const float* __restrict__ img, const float* __restrict__ g,
    const float* __restrict__ b, bf16* __restrict__ out) {
  int t = blockIdx.x;
  int bi = t / NTOK, n = t % NTOK;
  int ph = n / 14, pw = n % 14;
  __shared__ float vals[PD];
  __shared__ float part[8];
  int tid = threadIdx.x;
  int lane = tid & 63, wv = tid >> 6;
  for (int j = tid; j < PD; j += 256) {
    int p1 = j / 48, rem = j % 48, p2 = rem / 3, c = rem % 3;
    vals[j] = img[(((long)bi*3 + c)*224 + (ph*16 + p1))*224 + (pw*16 + p2)];
  }
  __syncthreads();
  float s = 0.f;
  for (int j = tid; j < PD; j += 256) s += vals[j];
  #pragma unroll
  for (int off = 1; off < 64; off <<= 1) s += __shfl_xor(s, off);
  if (lane == 0) part[wv] = s;
  __syncthreads();
  float mean = (part[0]+part[1]+part[2]+part[3]) / (float)PD;
  float s2 = 0.f;
  for (int j = tid; j < PD; j += 256) { float d = vals[j]-mean; s2 += d*d; }
  #pragma unroll
  for (int off = 1; off < 64; off <<= 1) s2 += __shfl_xor(s2, off);
  if (lane == 0) part[4+wv] = s2;
  __syncthreads();
  float rstd = rsqrtf((part[4]+part[5]+part[6]+part[7])/(float)PD + LN_EPS);
  for (int j = tid; j < PD; j += 256)
    out[(long)t*PD + j] = __float2bfloat16((vals[j]-mean)*rstd*g[j] + b[j]);
}

// ================= LayerNorm rows (dim=1024): optional fp32 out, optional bf16 out =================
__global__ __launch_bounds__(256) void ln_rows2(
    const float* __restrict__ in, const float* __restrict__ g,
    const float* __restrict__ b, const float* __restrict__ pos,
    float* __restrict__ outf, ushort4* __restrict__ outb) {
  long t = blockIdx.x;
  int tid = threadIdx.x;
  int lane = tid & 63, wv = tid >> 6;
  float4 v = ((const float4*)(in + t*DIMD))[tid];
  float s  = v.x+v.y+v.z+v.w;
  float s2 = v.x*v.x+v.y*v.y+v.z*v.z+v.w*v.w;
  #pragma unroll
  for (int off = 1; off < 64; off <<= 1) {
    s  += __shfl_xor(s, off);
    s2 += __shfl_xor(s2, off);
  }
  __shared__ float ps[4], pq[4];
  if (lane == 0) { ps[wv] = s; pq[wv] = s2; }
  __syncthreads();
  s  = ps[0]+ps[1]+ps[2]+ps[3];
  s2 = pq[0]+pq[1]+pq[2]+pq[3];
  float mean = s*(1.f/1024.f);
  float var  = s2*(1.f/1024.f) - mean*mean;
  float rstd = rsqrtf(var + LN_EPS);
  float4 gg = ((const float4*)g)[tid];
  float4 bb = ((const float4*)b)[tid];
  float4 o;
  o.x = (v.x-mean)*rstd*gg.x + bb.x;
  o.y = (v.y-mean)*rstd*gg.y + bb.y;
  o.z = (v.z-mean)*rstd*gg.z + bb.z;
  o.w = (v.w-mean)*rstd*gg.w + bb.w;
  if (pos) {
    float4 pp = ((const float4*)(pos + (long)(t % NTOK)*DIMD))[tid];
    o.x += pp.x; o.y += pp.y; o.z += pp.z; o.w += pp.w;
  }
  if (outf) ((float4*)(outf + t*DIMD))[tid] = o;
  if (outb) {
    ushort4 u;
    u.x = bfbits(o.x); u.y = bfbits(o.y); u.z = bfbits(o.z); u.w = bfbits(o.w);
    outb[t*256 + tid] = u;
  }
}

// ================= cast + transpose weights: fp32 [R][C] -> bf16 [C][R] =================
__global__ void castT(const float* __restrict__ src, bf16* __restrict__ dst, int R, int C) {
  __shared__ float t[32][33];
  int rb = blockIdx.y*32, cb = blockIdx.x*32;
  int tx = threadIdx.x, ty = threadIdx.y;  // (32,8)
  for (int i = ty; i < 32; i += 8)
    if (rb+i < R && cb+tx < C) t[i][tx] = src[(long)(rb+i)*C + cb+tx];
  __syncthreads();
  for (int i = ty; i < 32; i += 8)
    if (cb+i < C && rb+tx < R) dst[(long)(cb+i)*R + rb+tx] = __float2bfloat16(t[tx][i]);
}

// ================= natural cast fp32 -> bf16 (elementwise, float4) =================
__global__ __launch_bounds__(256) void castN(
    const float* __restrict__ src, ushort4* __restrict__ dst) {
  int i = blockIdx.x*256 + threadIdx.x;
  float4 v = ((const float4*)src)[i];
  ushort4 u;
  u.x = bfbits(v.x); u.y = bfbits(v.y); u.z = bfbits(v.z); u.w = bfbits(v.w);
  dst[i] = u;
}

// ================= mean over tokens -> bf16 =================
__global__ __launch_bounds__(256) void mean_tokens(
    const float* __restrict__ x, bf16* __restrict__ outb) {
  int b = blockIdx.x;
  int d = blockIdx.y*256 + threadIdx.x;
  const float* p = x + (long)b*NTOK*DIMD + d;
  float s = 0.f;
  #pragma unroll 4
  for (int n = 0; n < NTOK; n++) s += p[(long)n*DIMD];
  outb[(long)b*DIMD + d] = __float2bfloat16(s * (1.f/196.f));
}

extern "C" void kernel_launch(void* const* d_in, const int* in_sizes, int n_in,
                              void* d_out, int out_size, void* d_ws, size_t ws_size,
                              hipStream_t stream) {
  (void)in_sizes; (void)n_in; (void)out_size; (void)ws_size;
  const float* image = (const float*)d_in[0];
  const float* ln1_g = (const float*)d_in[1];
  const float* ln1_b = (const float*)d_in[2];
  const float* W_emb = (const float*)d_in[3];
  const float* b_emb = (const float*)d_in[4];
  const float* ln2_g = (const float*)d_in[5];
  const float* ln2_b = (const float*)d_in[6];
  const float* pos   = (const float*)d_in[7];
  const float* norm_g= (const float*)d_in[8];
  const float* norm_b= (const float*)d_in[9];
  const float* WV    = (const float*)d_in[10];
  const float* WK    = (const float*)d_in[11];
  const float* WQ    = (const float*)d_in[12];
  const float* lastW = (const float*)d_in[13];
  const float* lastb = (const float*)d_in[14];
  float* out = (float*)d_out;

  char* W = (char*)d_ws;
  float* x     = (float*)(W);                      // 51,380,224
  bf16*  xnb   = (bf16*) (W + 51380224);           // 25,690,112
  bf16*  xm    = (bf16*) (W + 77070336);           // 25.7MB in 51.6MB slab (alias Xp; overread zone)
  bf16*  Xp    = xm;
  // slabB: embed-phase xn (fp32 51.4 MB) OR layer-phase Gt+Apad
  float* xn    = (float*)(W + 128712704);
  bf16*  Gt    = (bf16*) (W + 128712704);          // 33,554,432 (64 x 1024 x 256 bf16)
  bf16*  Apad  = (bf16*) (W + 162267136);          //  8,388,608 (64 x 256 x 256 bf16)
  bf16*  WembT = (bf16*) (W + 180092928);          //  1,572,864
  bf16*  WQb   = (bf16*) (W + 181665792);          //  2,097,152 (natural layout)
  bf16*  WKb   = (bf16*) (W + 183762944);          //  2,097,152 (natural layout)
  bf16*  WVt   = (bf16*) (W + 185860096);          //     32,768
  bf16*  lastWT= (bf16*) (W + 185892864);          //  2,097,152
  bf16*  meanxb= (bf16*) (W + 187990016);          //    131,072
  float* clsPart=(float*)(W + 188121088);          //  2,097,152
  bf16*  Mt    = (bf16*) (W + 190218240);          //  2,097,152 (M^T = WK @ WQ^T)

  dim3 blk(256);
  dim3 blk512(512);
  dim3 blk1024(1024);
  const float scale = 0.08838834764831845f;  // 128^-0.5
  const long ZR = 0;

  // weight casts
  castT<<<dim3(32, 24), dim3(32, 8), 0, stream>>>(W_emb, WembT, PD, DIMD);
  castN<<<1024, blk, 0, stream>>>(WQ, (ushort4*)WQb);
  castN<<<1024, blk, 0, stream>>>(WK, (ushort4*)WKb);
  castT<<<dim3(4, 4),  dim3(32, 8), 0, stream>>>(WV, WVt, HD, HD);
  castT<<<dim3(32, 32), dim3(32, 8), 0, stream>>>(lastW, lastWT, DIMD, 1000);
  // Mt[j][i] = sum_k WK[j][k]*WQ[i][k]  (= (WQ @ WK^T)^T); M=1024 -> 4 x 256-row tiles
  gemm_mfma<<<dim3(8, 4, 1), blk512, 0, stream>>>(
      WKb, DIMD, ZR, WQb, DIMD, ZR, DIMD, 1,
      nullptr, Mt, DIMD, ZR, nullptr, nullptr, ZR, 1.f, DIMD, DIMD);

  // patch embed  (M=12544 = 49 x 256 exactly)
  patchify_ln<<<TOKENS, blk, 0, stream>>>(image, ln1_g, ln1_b, Xp);
  gemm_mfma<<<dim3(8, 49, 1), blk512, 0, stream>>>(
      Xp, PD, ZR, WembT, PD, ZR, PD, 0,
      xn, nullptr, DIMD, ZR, b_emb, nullptr, ZR, 1.f, TOKENS, DIMD);
  ln_rows2<<<TOKENS, blk, 0, stream>>>(xn, ln2_g, ln2_b, pos, x, nullptr);

  for (int l = 0; l < DEPTH; l++) {
    // xnb = bf16(LN(x))
    ln_rows2<<<TOKENS, blk, 0, stream>>>(x, norm_g, norm_b, nullptr, nullptr, (ushort4*)xnb);
    // xm = xnb @ M
    gemm_mfma<<<dim3(8, 49, 1), blk512, 0, stream>>>(
        xnb, DIMD, ZR, Mt, DIMD, ZR, DIMD, 1,
        nullptr, xm, DIMD, ZR, nullptr, nullptr, ZR, 1.f, TOKENS, DIMD);
    // Apad = softmax(xm @ xnb^T * scale), fused, pads (rows>=196, cols>=196) zeroed
    gemm_qs<<<dim3(1, 4, BATCH), blk, 0, stream>>>(xm, xnb, Apad, scale);
    // Gt[b][dim][tok] = WV^T @ xn^T  (direct transposed layout, pad cols zeroed)
    gemm_v<<<dim3(2, HEADS, BATCH), blk, 0, stream>>>(WVt, xnb, Gt);
    // x = Apad @ G + xnb (bf16 residual): 256x256 tile, Apad staged 4x instead of 8x
    gemm_av256<<<dim3(4, 1, BATCH), blk1024, 0, stream>>>(Apad, Gt, xnb, x);
  }

  // classifier
  mean_tokens<<<dim3(BATCH, 4), blk, 0, stream>>>(x, meanxb);
  gemm_cls<<<dim3(8, 8), blk, 0, stream>>>(meanxb, lastWT, clsPart);
  cls_reduce<<<250, blk, 0, stream>>>(clsPart, lastb, out);
}

// Round 14
// 967.557 us; speedup vs baseline: 1.3489x; 1.0383x over previous
//
#include <hip/hip_runtime.h>
#include <hip/hip_bf16.h>
#include <math.h>

#define NTOK   196
#define BATCH  64
#define TOKENS (BATCH*NTOK)   // 12544
#define DIMD   1024
#define PD     768
#define HEADS  8
#define HD     128
#define DEPTH  6
#define LN_EPS 1e-5f
#define APAD_R 256            // padded A rows per batch (for 256-row tiles)
#define APAD_C 256            // padded K dim for A@G (4*64; cols 196..256 zeroed)

typedef __hip_bfloat16 bf16;
typedef __attribute__((ext_vector_type(8))) short bf16x8;
typedef __attribute__((ext_vector_type(4))) float f32x4;

typedef const __attribute__((address_space(1))) void* gptr_t;
typedef __attribute__((address_space(3))) void* lptr_t;

__device__ __forceinline__ void gl_lds16(const bf16* g, bf16* l) {
  __builtin_amdgcn_global_load_lds((gptr_t)(const void*)g, (lptr_t)(void*)l, 16, 0, 0);
}
__device__ __forceinline__ unsigned short bfbits(float f) {
  bf16 h = __float2bfloat16(f);
  return *(unsigned short*)&h;
}

// XCD-aware bijective swizzle (requires nwg % 8 == 0, true for all call sites):
// physical block f runs work item (f%8)*(nwg/8) + f/8, so each XCD gets a
// CONTIGUOUS range of work ids -> operand-panel-sharing blocks co-locate on one L2.
__device__ __forceinline__ void xcd_swizzle(int& bx, int& by, int& bz) {
  const int gx = gridDim.x, gy = gridDim.y;
  const int nwg = gx*gy*gridDim.z;
  const int flat = blockIdx.x + gx*(blockIdx.y + gy*blockIdx.z);
  const int swz = (flat & 7)*(nwg >> 3) + (flat >> 3);
  bx = swz % gx;
  const int rest = swz / gx;
  by = rest % gy;
  bz = rest / gy;
}

// ================= generic MFMA GEMM: C[m][n] = sum_k A[m][k] * Bt[n][k] =================
// 256x128 tile, 512 threads (8 waves, each a 64x64 quadrant: 4 rows x 2 cols of waves),
// BK=64 (two [.][32] chunks per barrier pair). Measured r11: staging service ~6 TB/s
// at this shape. Single LDS buffer 48 KB -> 3 blocks/CU. K-accumulation order per
// fragment unchanged -> bit-identical output.
// mode 0: Cf = acc*alpha (+bias)(+bf16 res); mode 1: Cb = bf16(acc)
__global__ __launch_bounds__(512) void gemm_mfma(
    const bf16* __restrict__ A, int lda, long aStride,
    const bf16* __restrict__ Bt, int ldb, long bStride,
    int K, int mode,
    float* __restrict__ Cf, bf16* __restrict__ Cb, int ldc, long cStride,
    const float* __restrict__ bias, const bf16* __restrict__ resb, long resStride,
    float alpha, int Mb, int Nb) {
  __shared__ __align__(16) bf16 As[2*256*32];   // 32 KB (2 chunks x 256 rows x 32 cols)
  __shared__ __align__(16) bf16 Bs[2*128*32];   // 16 KB
  const int CHA = 256*32, CHB = 128*32;
  int bx, by, bz;
  xcd_swizzle(bx, by, bz);
  const int z = bz;
  A  += (long)z*aStride;
  Bt += (long)z*bStride;
  const int m0 = by*256, n0 = bx*128;
  const int tid = threadIdx.x, lane = tid & 63, wv = tid >> 6;   // wv 0..7
  const int lrow = lane >> 2, lchunk = lane & 3;
  const bf16* ga = A + (long)(m0 + wv*32 + lrow)*lda + lchunk*8;
  const bf16* gb = Bt + (long)(n0 + wv*16 + lrow)*ldb + lchunk*8;
  bf16* lA = As + (wv*32)*32;
  bf16* lB = Bs + (wv*16)*32;
  const int mBase = (wv >> 1)*64, nBase = (wv & 1)*64;
  const int fr = lane & 15, fq = lane >> 4;

  f32x4 acc[4][4];
  #pragma unroll
  for (int i = 0; i < 4; i++)
    #pragma unroll
    for (int j = 0; j < 4; j++) acc[i][j] = (f32x4){0.f,0.f,0.f,0.f};

  const int nk = K >> 6;   // BK=64; all call sites have K % 64 == 0
  for (int t = 0; t < nk; ++t) {
    const int k0 = t << 6;
    #pragma unroll
    for (int c = 0; c < 2; c++) {
      gl_lds16(ga + k0 + c*32,          lA + c*CHA);
      gl_lds16(ga + k0 + c*32 + 16*lda, lA + c*CHA + 16*32);
      gl_lds16(gb + k0 + c*32,          lB + c*CHB);
    }
    asm volatile("s_waitcnt vmcnt(0)" ::: "memory");
    __syncthreads();
    #pragma unroll
    for (int c = 0; c < 2; c++) {
      const bf16* Ab = As + c*CHA;
      const bf16* Bb = Bs + c*CHB;
      bf16x8 af[4], bfr[4];
      #pragma unroll
      for (int mi = 0; mi < 4; mi++)
        af[mi] = *(const bf16x8*)(Ab + (mBase + mi*16 + fr)*32 + fq*8);
      #pragma unroll
      for (int ni = 0; ni < 4; ni++)
        bfr[ni] = *(const bf16x8*)(Bb + (nBase + ni*16 + fr)*32 + fq*8);
      #pragma unroll
      for (int mi = 0; mi < 4; mi++)
        #pragma unroll
        for (int ni = 0; ni < 4; ni++)
          acc[mi][ni] = __builtin_amdgcn_mfma_f32_16x16x32_bf16(af[mi], bfr[ni], acc[mi][ni], 0, 0, 0);
    }
    __syncthreads();
  }

  #pragma unroll
  for (int mi = 0; mi < 4; mi++)
    #pragma unroll
    for (int ni = 0; ni < 4; ni++)
      #pragma unroll
      for (int r = 0; r < 4; r++) {
        int gm = m0 + mBase + mi*16 + fq*4 + r;
        int gn = n0 + nBase + ni*16 + fr;
        if (gm >= Mb || gn >= Nb) continue;
        float v = acc[mi][ni][r] * alpha;
        if (mode == 0) {
          if (bias) v += bias[gn];
          if (resb) v += __bfloat162float(resb[(long)z*resStride + (long)gm*ldc + gn]);
          Cf[(long)z*cStride + (long)gm*ldc + gn] = v;
        } else {
          Cb[(long)z*cStride + (long)gm*ldc + gn] = __float2bfloat16(v);
        }
      }
}

// ================= AV GEMM, 256x256 tile: x[z] = Apad[z] @ Gt[z]^T + xnb[z] =================
// 1024 threads, 16 waves (4M x 4N), each wave the SAME proven 64x64 quadrant / 16xf32x4
// accumulator as gemm_mfma. BK=64, K=256 (padded; cols [196,256) zero on both operands).
__global__ __launch_bounds__(1024) void gemm_av256(
    const bf16* __restrict__ Apad, const bf16* __restrict__ Gt,
    const bf16* __restrict__ resb, float* __restrict__ Cf) {
  __shared__ __align__(16) bf16 As[2*256*32];   // 32 KB
  __shared__ __align__(16) bf16 Bs[2*256*32];   // 32 KB
  const int CH = 256*32;
  int bx, by, bz;
  xcd_swizzle(bx, by, bz);
  (void)by;
  const int z = bz, n0 = bx*256;
  const int tid = threadIdx.x, lane = tid & 63, wv = tid >> 6;   // wv 0..15
  const int lrow = lane >> 2, lchunk = lane & 3;
  const bf16* ga = Apad + ((long)z*APAD_R + wv*16 + lrow)*APAD_C + lchunk*8;
  const bf16* gb = Gt   + ((long)z*DIMD  + n0 + wv*16 + lrow)*APAD_C + lchunk*8;
  bf16* lA = As + (wv*16)*32;
  bf16* lB = Bs + (wv*16)*32;
  const int mBase = (wv >> 2)*64, nBase = (wv & 3)*64;
  const int fr = lane & 15, fq = lane >> 4;

  f32x4 acc[4][4];
  #pragma unroll
  for (int i = 0; i < 4; i++)
    #pragma unroll
    for (int j = 0; j < 4; j++) acc[i][j] = (f32x4){0.f,0.f,0.f,0.f};

  const int nk = APAD_C >> 6;   // 4
  for (int t = 0; t < nk; ++t) {
    const int k0 = t << 6;
    #pragma unroll
    for (int c = 0; c < 2; c++) {
      gl_lds16(ga + k0 + c*32, lA + c*CH);
      gl_lds16(gb + k0 + c*32, lB + c*CH);
    }
    asm volatile("s_waitcnt vmcnt(0)" ::: "memory");
    __syncthreads();
    #pragma unroll
    for (int c = 0; c < 2; c++) {
      const bf16* Ab = As + c*CH;
      const bf16* Bb = Bs + c*CH;
      bf16x8 af[4], bfr[4];
      #pragma unroll
      for (int mi = 0; mi < 4; mi++)
        af[mi] = *(const bf16x8*)(Ab + (mBase + mi*16 + fr)*32 + fq*8);
      #pragma unroll
      for (int ni = 0; ni < 4; ni++)
        bfr[ni] = *(const bf16x8*)(Bb + (nBase + ni*16 + fr)*32 + fq*8);
      #pragma unroll
      for (int mi = 0; mi < 4; mi++)
        #pragma unroll
        for (int ni = 0; ni < 4; ni++)
          acc[mi][ni] = __builtin_amdgcn_mfma_f32_16x16x32_bf16(af[mi], bfr[ni], acc[mi][ni], 0, 0, 0);
    }
    __syncthreads();
  }

  #pragma unroll
  for (int mi = 0; mi < 4; mi++)
    #pragma unroll
    for (int ni = 0; ni < 4; ni++)
      #pragma unroll
      for (int r = 0; r < 4; r++) {
        int gm = mBase + mi*16 + fq*4 + r;
        int gn = n0 + nBase + ni*16 + fr;
        if (gm >= NTOK) continue;
        float v = acc[mi][ni][r]
                + __bfloat162float(resb[(long)z*NTOK*DIMD + (long)gm*DIMD + gn]);
        Cf[(long)z*NTOK*DIMD + (long)gm*DIMD + gn] = v;
      }
}

// ====== FUSED qs+v (grid union): 20 work items per batch, 64 batches = 1280 blocks ======
// Work r<4: QKT+softmax 64-row tile (reads xm,xnb -> writes Apad).
// Work r>=4: V-GEMM block vr=r-4: h=vr>>1, n0=(vr&1)*128 (reads WVt,xnb -> writes Gt).
// The two workloads are data-independent (disjoint writes; both read xnb) and have
// complementary shapes: qs = 256 long blocks (was 1/CU, no latency partner), v = 1024
// short one-shot blocks. Union LDS 64 KB -> 2 blocks/CU, so every qs block co-resides
// with another block that absorbs its stage stalls. Bodies verbatim from the proven
// gemm_qs / gemm_v -> bit-identical math.
__global__ __launch_bounds__(256) void gemm_qsv(
    const bf16* __restrict__ xmp, const bf16* __restrict__ xnbp,
    bf16* __restrict__ Apad, float scale,
    const bf16* __restrict__ WVt, bf16* __restrict__ Gt) {
  __shared__ __align__(16) char smem[65536];
  const int nwg = gridDim.x * gridDim.y;        // 20 * 64 = 1280
  const int flat = blockIdx.x + gridDim.x*blockIdx.y;
  const int swz = (flat & 7)*(nwg >> 3) + (flat >> 3);
  const int z = swz / 20;
  const int r = swz % 20;
  const int tid = threadIdx.x, lane = tid & 63, wv = tid >> 6;
  const int lrow = lane >> 2, lchunk = lane & 3;
  const int fr = lane & 15, fq = lane >> 4;

  if (r < 4) {
    // ---------------- qs body ----------------
    bf16* As = (bf16*)smem;                 // 3 x 64x32  = 12 KB
    bf16* Bs = (bf16*)(smem + 12288);       // 3 x 224x32 = 42 KB
    const int ABUF = 64*32, BBUF = 224*32;
    const int y0 = r*64;
    const bf16* A  = xmp  + (long)z*NTOK*DIMD;
    const bf16* Bt = xnbp + (long)z*NTOK*DIMD;
    const bf16* ga = A + (long)(y0 + wv*16 + lrow)*DIMD + lchunk*8;
    bf16* lA = As + (wv*16)*32;
    const bf16* gb = Bt + (long)(wv*64 + lrow)*DIMD + lchunk*8;
    bf16* lB = Bs + (wv*64)*32;
    const int nIss = (wv < 3) ? 4 : 2;

    f32x4 acc[14];
    #pragma unroll
    for (int j = 0; j < 14; j++) acc[j] = (f32x4){0.f,0.f,0.f,0.f};

    const int nk = 32;
    #pragma unroll
    for (int p = 0; p < 2; p++) {
      gl_lds16(ga + p*32, lA + p*ABUF);
      for (int i = 0; i < nIss; i++)
        gl_lds16(gb + p*32 + (long)i*16*DIMD, lB + p*BBUF + i*16*32);
    }
    for (int t = 0; t < nk; ++t) {
      const int cur = t % 3;
      if (t + 2 < nk) {
        const int nb = (t + 2) % 3;
        const int k2 = (t + 2) << 5;
        gl_lds16(ga + k2, lA + nb*ABUF);
        for (int i = 0; i < nIss; i++)
          gl_lds16(gb + k2 + (long)i*16*DIMD, lB + nb*BBUF + i*16*32);
      }
      const int ahead = (nk - 1 - t > 2) ? 2 : (nk - 1 - t);
      if (wv < 3) {      // 5 loads/stage
        if (ahead == 2)      asm volatile("s_waitcnt vmcnt(10)" ::: "memory");
        else if (ahead == 1) asm volatile("s_waitcnt vmcnt(5)"  ::: "memory");
        else                 asm volatile("s_waitcnt vmcnt(0)"  ::: "memory");
      } else {           // 3 loads/stage
        if (ahead == 2)      asm volatile("s_waitcnt vmcnt(6)"  ::: "memory");
        else if (ahead == 1) asm volatile("s_waitcnt vmcnt(3)"  ::: "memory");
        else                 asm volatile("s_waitcnt vmcnt(0)"  ::: "memory");
      }
      __builtin_amdgcn_s_barrier();
      const bf16* Ab = As + cur*ABUF;
      const bf16* Bb = Bs + cur*BBUF;
      bf16x8 af = *(const bf16x8*)(Ab + (wv*16 + fr)*32 + fq*8);
      #pragma unroll
      for (int j = 0; j < 14; j++) {
        bf16x8 bfr = *(const bf16x8*)(Bb + (j*16 + fr)*32 + fq*8);
        acc[j] = __builtin_amdgcn_mfma_f32_16x16x32_bf16(af, bfr, acc[j], 0, 0, 0);
      }
      asm volatile("s_waitcnt lgkmcnt(0)" ::: "memory");
      __builtin_amdgcn_s_barrier();
    }

    const bf16 bzero = __float2bfloat16(0.f);
    #pragma unroll
    for (int rr = 0; rr < 4; rr++) {
      float mx = -INFINITY;
      #pragma unroll
      for (int j = 0; j < 14; j++) {
        int col = j*16 + fr;
        if (col < NTOK) mx = fmaxf(mx, acc[j][rr]);
      }
      #pragma unroll
      for (int off = 1; off < 16; off <<= 1) mx = fmaxf(mx, __shfl_xor(mx, off));
      float e[14];
      float s = 0.f;
      #pragma unroll
      for (int j = 0; j < 14; j++) {
        int col = j*16 + fr;
        e[j] = (col < NTOK) ? __expf((acc[j][rr] - mx) * scale) : 0.f;
        s += e[j];
      }
      #pragma unroll
      for (int off = 1; off < 16; off <<= 1) s += __shfl_xor(s, off);
      float inv = 1.f / s;
      int grow = y0 + wv*16 + fq*4 + rr;
      bf16* dst = Apad + ((long)z*APAD_R + grow)*APAD_C;
      #pragma unroll
      for (int j = 0; j < 14; j++) {
        int col = j*16 + fr;
        float outv = (grow < NTOK) ? e[j]*inv : 0.f;   // col>=196 -> e=0 -> writes 0
        dst[col] = __float2bfloat16(outv);
      }
      dst[224 + fr] = bzero;   // zero-fill padded K cols [224,256)
      dst[240 + fr] = bzero;
    }
  } else {
    // ---------------- v body ----------------
    bf16* As = (bf16*)smem;                 // 4 x 128x32 = 32 KB
    bf16* Bs = (bf16*)(smem + 32768);       // 4 x 128x32 = 32 KB
    const int CH = 128*32;
    const int vr = r - 4;                   // 0..15
    const int h = vr >> 1, n0 = (vr & 1)*128;
    const bf16* ga = WVt + (long)(wv*32 + lrow)*HD + lchunk*8;
    const bf16* gb = xnbp + (long)(z*NTOK + n0 + wv*32 + lrow)*DIMD + h*HD + lchunk*8;
    bf16* lA = As + (wv*32)*32;
    bf16* lB = Bs + (wv*32)*32;
    const int mBase = (wv & 1)*64, nBase = (wv >> 1)*64;

    f32x4 acc[4][4];
    #pragma unroll
    for (int i = 0; i < 4; i++)
      #pragma unroll
      for (int j = 0; j < 4; j++) acc[i][j] = (f32x4){0.f,0.f,0.f,0.f};

    #pragma unroll
    for (int c = 0; c < 4; c++) {
      gl_lds16(ga + c*32,           lA + c*CH);
      gl_lds16(ga + c*32 + 16*HD,   lA + c*CH + 16*32);
      gl_lds16(gb + c*32,           lB + c*CH);
      gl_lds16(gb + c*32 + 16*DIMD, lB + c*CH + 16*32);
    }
    asm volatile("s_waitcnt vmcnt(0)" ::: "memory");
    __syncthreads();

    #pragma unroll
    for (int c = 0; c < 4; c++) {
      const bf16* Ab = As + c*CH;
      const bf16* Bb = Bs + c*CH;
      bf16x8 af[4], bfr[4];
      #pragma unroll
      for (int mi = 0; mi < 4; mi++)
        af[mi] = *(const bf16x8*)(Ab + (mBase + mi*16 + fr)*32 + fq*8);
      #pragma unroll
      for (int ni = 0; ni < 4; ni++)
        bfr[ni] = *(const bf16x8*)(Bb + (nBase + ni*16 + fr)*32 + fq*8);
      #pragma unroll
      for (int mi = 0; mi < 4; mi++)
        #pragma unroll
        for (int ni = 0; ni < 4; ni++)
          acc[mi][ni] = __builtin_amdgcn_mfma_f32_16x16x32_bf16(af[mi], bfr[ni], acc[mi][ni], 0, 0, 0);
    }

    #pragma unroll
    for (int mi = 0; mi < 4; mi++)
      #pragma unroll
      for (int ni = 0; ni < 4; ni++)
        #pragma unroll
        for (int rr = 0; rr < 4; rr++) {
          int gm = mBase + mi*16 + fq*4 + rr;       // output dim within head (0..127)
          int gn = n0 + nBase + ni*16 + fr;         // token
          if (gn < NTOK)
            Gt[((long)z*DIMD + h*HD + gm)*APAD_C + gn] = __float2bfloat16(acc[mi][ni][rr]);
          else if (gn < APAD_C)
            Gt[((long)z*DIMD + h*HD + gm)*APAD_C + gn] = __float2bfloat16(0.f);
        }
  }
}

// ================= classifier split-K (K=128: full up-front staging) =================
__global__ __launch_bounds__(256) void gemm_cls(
    const bf16* __restrict__ A, const bf16* __restrict__ Bt,
    float* __restrict__ Cp) {
  __shared__ __align__(16) bf16 As[4][64*32];    // 16 KB
  __shared__ __align__(16) bf16 Bs[4][128*32];   // 32 KB
  const int ACH = 64*32, BCH = 128*32;
  const int n0 = blockIdx.x*128, kz = blockIdx.y;
  const int tid = threadIdx.x, lane = tid & 63, wv = tid >> 6;
  const bf16* ga = A + (tid>>2)*DIMD + kz*128 + (tid&3)*8;
  const bf16* gb = Bt + (long)(n0 + wv*32 + (lane>>2))*DIMD + kz*128 + (lane&3)*8;
  bf16* lA = &As[0][wv*512];
  bf16* lB = &Bs[0][(wv*32)*32];
  const int fr = lane & 15, fq = lane >> 4;
  f32x4 acc[4][2];
  #pragma unroll
  for (int i = 0; i < 4; i++)
    #pragma unroll
    for (int j = 0; j < 2; j++) acc[i][j] = (f32x4){0.f,0.f,0.f,0.f};
  #pragma unroll
  for (int it = 0; it < 4; it++) {
    gl_lds16(ga + it*32, lA + it*ACH);
    gl_lds16(gb + it*32,            lB + it*BCH);
    gl_lds16(gb + it*32 + 16*DIMD,  lB + it*BCH + 16*32);
  }
  asm volatile("s_waitcnt vmcnt(0)" ::: "memory");
  __syncthreads();
  #pragma unroll
  for (int it = 0; it < 4; it++) {
    const bf16* Ab = &As[it][0];
    const bf16* Bb = &Bs[it][0];
    bf16x8 af[4], bfr[2];
    #pragma unroll
    for (int mi = 0; mi < 4; mi++)
      af[mi] = *(const bf16x8*)(Ab + (mi*16 + fr)*32 + fq*8);
    #pragma unroll
    for (int ni = 0; ni < 2; ni++)
      bfr[ni] = *(const bf16x8*)(Bb + (wv*32 + ni*16 + fr)*32 + fq*8);
    #pragma unroll
    for (int mi = 0; mi < 4; mi++)
      #pragma unroll
      for (int ni = 0; ni < 2; ni++)
        acc[mi][ni] = __builtin_amdgcn_mfma_f32_16x16x32_bf16(af[mi], bfr[ni], acc[mi][ni], 0, 0, 0);
  }
  #pragma unroll
  for (int mi = 0; mi < 4; mi++)
    #pragma unroll
    for (int ni = 0; ni < 2; ni++)
      #pragma unroll
      for (int r = 0; r < 4; r++) {
        int gm = mi*16 + fq*4 + r;
        int gn = n0 + wv*32 + ni*16 + fr;
        Cp[((long)kz*64 + gm)*DIMD + gn] = acc[mi][ni][r];
      }
}

__global__ __launch_bounds__(256) void cls_reduce(
    const float* __restrict__ Cp, const float* __restrict__ bias,
    float* __restrict__ out) {
  int i = blockIdx.x*256 + threadIdx.x;
  int m = i / 1000, n = i - m*1000;
  float s = bias[n];
  #pragma unroll
  for (int kz = 0; kz < 8; kz++) s += Cp[((long)kz*64 + m)*DIMD + n];
  out[i] = s;
}

// ================= patchify + LN1 (dim 768) -> bf16 =================
__global__ __launch_bounds__(256) void patchify_ln(
    const float* __restrict__ img, const float* __restrict__ g,
    const float* __restrict__ b, bf16* __restrict__ out) {
  int t = blockIdx.x;
  int bi = t / NTOK, n = t % NTOK;
  int ph = n / 14, pw = n % 14;
  __shared__ float vals[PD];
  __shared__ float part[8];
  int tid = threadIdx.x;
  int lane = tid & 63, wv = tid >> 6;
  for (int j = tid; j < PD; j += 256) {
    int p1 = j / 48, rem = j % 48, p2 = rem / 3, c = rem % 3;
    vals[j] = img[(((long)bi*3 + c)*224 + (ph*16 + p1))*224 + (pw*16 + p2)];
  }
  __syncthreads();
  float s = 0.f;
  for (int j = tid; j < PD; j += 256) s += vals[j];
  #pragma unroll
  for (int off = 1; off < 64; off <<= 1) s += __shfl_xor(s, off);
  if (lane == 0) part[wv] = s;
  __syncthreads();
  float mean = (part[0]+part[1]+part[2]+part[3]) / (float)PD;
  float s2 = 0.f;
  for (int j = tid; j < PD; j += 256) { float d = vals[j]-mean; s2 += d*d; }
  #pragma unroll
  for (int off = 1; off < 64; off <<= 1) s2 += __shfl_xor(s2, off);
  if (lane == 0) part[4+wv] = s2;
  __syncthreads();
  float rstd = rsqrtf((part[4]+part[5]+part[6]+part[7])/(float)PD + LN_EPS);
  for (int j = tid; j < PD; j += 256)
    out[(long)t*PD + j] = __float2bfloat16((vals[j]-mean)*rstd*g[j] + b[j]);
}

// ================= LayerNorm rows (dim=1024): optional fp32 out, optional bf16 out =================
__global__ __launch_bounds__(256) void ln_rows2(
    const float* __restrict__ in, const float* __restrict__ g,
    const float* __restrict__ b, const float* __restrict__ pos,
    float* __restrict__ outf, ushort4* __restrict__ outb) {
  long t = blockIdx.x;
  int tid = threadIdx.x;
  int lane = tid & 63, wv = tid >> 6;
  float4 v = ((const float4*)(in + t*DIMD))[tid];
  float s  = v.x+v.y+v.z+v.w;
  float s2 = v.x*v.x+v.y*v.y+v.z*v.z+v.w*v.w;
  #pragma unroll
  for (int off = 1; off < 64; off <<= 1) {
    s  += __shfl_xor(s, off);
    s2 += __shfl_xor(s2, off);
  }
  __shared__ float ps[4], pq[4];
  if (lane == 0) { ps[wv] = s; pq[wv] = s2; }
  __syncthreads();
  s  = ps[0]+ps[1]+ps[2]+ps[3];
  s2 = pq[0]+pq[1]+pq[2]+pq[3];
  float mean = s*(1.f/1024.f);
  float var  = s2*(1.f/1024.f) - mean*mean;
  float rstd = rsqrtf(var + LN_EPS);
  float4 gg = ((const float4*)g)[tid];
  float4 bb = ((const float4*)b)[tid];
  float4 o;
  o.x = (v.x-mean)*rstd*gg.x + bb.x;
  o.y = (v.y-mean)*rstd*gg.y + bb.y;
  o.z = (v.z-mean)*rstd*gg.z + bb.z;
  o.w = (v.w-mean)*rstd*gg.w + bb.w;
  if (pos) {
    float4 pp = ((const float4*)(pos + (long)(t % NTOK)*DIMD))[tid];
    o.x += pp.x; o.y += pp.y; o.z += pp.z; o.w += pp.w;
  }
  if (outf) ((float4*)(outf + t*DIMD))[tid] = o;
  if (outb) {
    ushort4 u;
    u.x = bfbits(o.x); u.y = bfbits(o.y); u.z = bfbits(o.z); u.w = bfbits(o.w);
    outb[t*256 + tid] = u;
  }
}

// ================= cast + transpose weights: fp32 [R][C] -> bf16 [C][R] =================
__global__ void castT(const float* __restrict__ src, bf16* __restrict__ dst, int R, int C) {
  __shared__ float t[32][33];
  int rb = blockIdx.y*32, cb = blockIdx.x*32;
  int tx = threadIdx.x, ty = threadIdx.y;  // (32,8)
  for (int i = ty; i < 32; i += 8)
    if (rb+i < R && cb+tx < C) t[i][tx] = src[(long)(rb+i)*C + cb+tx];
  __syncthreads();
  for (int i = ty; i < 32; i += 8)
    if (cb+i < C && rb+tx < R) dst[(long)(cb+i)*R + rb+tx] = __float2bfloat16(t[tx][i]);
}

// ================= natural cast fp32 -> bf16 (elementwise, float4) =================
__global__ __launch_bounds__(256) void castN(
    const float* __restrict__ src, ushort4* __restrict__ dst) {
  int i = blockIdx.x*256 + threadIdx.x;
  float4 v = ((const float4*)src)[i];
  ushort4 u;
  u.x = bfbits(v.x); u.y = bfbits(v.y); u.z = bfbits(v.z); u.w = bfbits(v.w);
  dst[i] = u;
}

// ================= mean over tokens -> bf16 =================
__global__ __launch_bounds__(256) void mean_tokens(
    const float* __restrict__ x, bf16* __restrict__ outb) {
  int b = blockIdx.x;
  int d = blockIdx.y*256 + threadIdx.x;
  const float* p = x + (long)b*NTOK*DIMD + d;
  float s = 0.f;
  #pragma unroll 4
  for (int n = 0; n < NTOK; n++) s += p[(long)n*DIMD];
  outb[(long)b*DIMD + d] = __float2bfloat16(s * (1.f/196.f));
}

extern "C" void kernel_launch(void* const* d_in, const int* in_sizes, int n_in,
                              void* d_out, int out_size, void* d_ws, size_t ws_size,
                              hipStream_t stream) {
  (void)in_sizes; (void)n_in; (void)out_size; (void)ws_size;
  const float* image = (const float*)d_in[0];
  const float* ln1_g = (const float*)d_in[1];
  const float* ln1_b = (const float*)d_in[2];
  const float* W_emb = (const float*)d_in[3];
  const float* b_emb = (const float*)d_in[4];
  const float* ln2_g = (const float*)d_in[5];
  const float* ln2_b = (const float*)d_in[6];
  const float* pos   = (const float*)d_in[7];
  const float* norm_g= (const float*)d_in[8];
  const float* norm_b= (const float*)d_in[9];
  const float* WV    = (const float*)d_in[10];
  const float* WK    = (const float*)d_in[11];
  const float* WQ    = (const float*)d_in[12];
  const float* lastW = (const float*)d_in[13];
  const float* lastb = (const float*)d_in[14];
  float* out = (float*)d_out;

  char* W = (char*)d_ws;
  float* x     = (float*)(W);                      // 51,380,224
  bf16*  xnb   = (bf16*) (W + 51380224);           // 25,690,112
  bf16*  xm    = (bf16*) (W + 77070336);           // 25.7MB in 51.6MB slab (alias Xp; overread zone)
  bf16*  Xp    = xm;
  // slabB: embed-phase xn (fp32 51.4 MB) OR layer-phase Gt+Apad
  float* xn    = (float*)(W + 128712704);
  bf16*  Gt    = (bf16*) (W + 128712704);          // 33,554,432 (64 x 1024 x 256 bf16)
  bf16*  Apad  = (bf16*) (W + 162267136);          //  8,388,608 (64 x 256 x 256 bf16)
  bf16*  WembT = (bf16*) (W + 180092928);          //  1,572,864
  bf16*  WQb   = (bf16*) (W + 181665792);          //  2,097,152 (natural layout)
  bf16*  WKb   = (bf16*) (W + 183762944);          //  2,097,152 (natural layout)
  bf16*  WVt   = (bf16*) (W + 185860096);          //     32,768
  bf16*  lastWT= (bf16*) (W + 185892864);          //  2,097,152
  bf16*  meanxb= (bf16*) (W + 187990016);          //    131,072
  float* clsPart=(float*)(W + 188121088);          //  2,097,152
  bf16*  Mt    = (bf16*) (W + 190218240);          //  2,097,152 (M^T = WK @ WQ^T)

  dim3 blk(256);
  dim3 blk512(512);
  dim3 blk1024(1024);
  const float scale = 0.08838834764831845f;  // 128^-0.5
  const long ZR = 0;

  // weight casts
  castT<<<dim3(32, 24), dim3(32, 8), 0, stream>>>(W_emb, WembT, PD, DIMD);
  castN<<<1024, blk, 0, stream>>>(WQ, (ushort4*)WQb);
  castN<<<1024, blk, 0, stream>>>(WK, (ushort4*)WKb);
  castT<<<dim3(4, 4),  dim3(32, 8), 0, stream>>>(WV, WVt, HD, HD);
  castT<<<dim3(32, 32), dim3(32, 8), 0, stream>>>(lastW, lastWT, DIMD, 1000);
  // Mt[j][i] = sum_k WK[j][k]*WQ[i][k]  (= (WQ @ WK^T)^T); M=1024 -> 4 x 256-row tiles
  gemm_mfma<<<dim3(8, 4, 1), blk512, 0, stream>>>(
      WKb, DIMD, ZR, WQb, DIMD, ZR, DIMD, 1,
      nullptr, Mt, DIMD, ZR, nullptr, nullptr, ZR, 1.f, DIMD, DIMD);

  // patch embed  (M=12544 = 49 x 256 exactly)
  patchify_ln<<<TOKENS, blk, 0, stream>>>(image, ln1_g, ln1_b, Xp);
  gemm_mfma<<<dim3(8, 49, 1), blk512, 0, stream>>>(
      Xp, PD, ZR, WembT, PD, ZR, PD, 0,
      xn, nullptr, DIMD, ZR, b_emb, nullptr, ZR, 1.f, TOKENS, DIMD);
  ln_rows2<<<TOKENS, blk, 0, stream>>>(xn, ln2_g, ln2_b, pos, x, nullptr);

  for (int l = 0; l < DEPTH; l++) {
    // xnb = bf16(LN(x))
    ln_rows2<<<TOKENS, blk, 0, stream>>>(x, norm_g, norm_b, nullptr, nullptr, (ushort4*)xnb);
    // xm = xnb @ M
    gemm_mfma<<<dim3(8, 49, 1), blk512, 0, stream>>>(
        xnb, DIMD, ZR, Mt, DIMD, ZR, DIMD, 1,
        nullptr, xm, DIMD, ZR, nullptr, nullptr, ZR, 1.f, TOKENS, DIMD);
    // fused: Apad = softmax(xm @ xnb^T * scale)  AND  Gt = WV^T @ xnb^T (grid union)
    gemm_qsv<<<dim3(20, 64), blk, 0, stream>>>(xm, xnb, Apad, scale, WVt, Gt);
    // x = Apad @ G + xnb (bf16 residual): 256x256 tile AV GEMM, K=256 padded
    gemm_av256<<<dim3(4, 1, BATCH), blk1024, 0, stream>>>(Apad, Gt, xnb, x);
  }

  // classifier
  mean_tokens<<<dim3(BATCH, 4), blk, 0, stream>>>(x, meanxb);
  gemm_cls<<<dim3(8, 8), blk, 0, stream>>>(meanxb, lastWT, clsPart);
  cls_reduce<<<250, blk, 0, stream>>>(clsPart, lastb, out);
}